// Round 13
// baseline (1472.161 us; speedup 1.0000x reference)
//
#include <hip/hip_runtime.h>
#include <stdint.h>

#define N_PATCH 8192
#define DIM     1024
#define HID     512
#define NHEAD   16

using i32x4 = __attribute__((ext_vector_type(4))) int;

__device__ __forceinline__ void gload_lds16(const void* g, void* l) {
  __builtin_amdgcn_global_load_lds(
      reinterpret_cast<const __attribute__((address_space(1))) void*>(
          reinterpret_cast<uintptr_t>(g)),
      reinterpret_cast<__attribute__((address_space(3))) void*>(
          reinterpret_cast<uintptr_t>(l)),
      16, 0, 0);
}

__device__ __forceinline__ int q8(float v, float rs) {
  int q = (int)rintf(v * rs);
  return q > 127 ? 127 : (q < -127 ? -127 : q);
}

// ---------------- prep1: quantize x per-row (bid<2048) + W column amax (bid>=2048, 256 blk) ----
__global__ void prep1_kernel(const float* __restrict__ x,
                             signed char* __restrict__ xq, float* __restrict__ sx,
                             const float* __restrict__ Vw, const float* __restrict__ Uw,
                             float* __restrict__ swp, float* __restrict__ rswp) {
  __shared__ float red[4][64];
  const int bid = blockIdx.x;
  const int t = threadIdx.x;
  if (bid < 2048) {            // ---- x: one wave per row, 4 rows/block ----
    const int row = bid * 4 + (t >> 6);
    const int lane = t & 63;
    const float* xr = x + (size_t)row * DIM;
    float4 v[4];
    float am = 0.f;
    #pragma unroll
    for (int j = 0; j < 4; ++j) {
      v[j] = *(const float4*)&xr[j * 256 + lane * 4];
      am = fmaxf(am, fmaxf(fmaxf(fabsf(v[j].x), fabsf(v[j].y)),
                           fmaxf(fabsf(v[j].z), fabsf(v[j].w))));
    }
    #pragma unroll
    for (int s = 32; s; s >>= 1) am = fmaxf(am, __shfl_xor(am, s, 64));
    const float rs = (am > 0.f) ? 127.f / am : 0.f;
    #pragma unroll
    for (int j = 0; j < 4; ++j) {
      int b = (q8(v[j].x, rs) & 255) | ((q8(v[j].y, rs) & 255) << 8) |
              ((q8(v[j].z, rs) & 255) << 16) | ((q8(v[j].w, rs) & 255) << 24);
      ((int*)xq)[row * 256 + j * 64 + lane] = b;
    }
    if (lane == 0) sx[row] = am / 127.f;
    return;
  }
  // ---- W column amax: 256 blocks = u(2) x k(16) x hc(8), 64 cols each ----
  const int b2 = bid - 2048;
  const int u = b2 >> 7, k = (b2 >> 3) & 15, hc = b2 & 7;
  const float* W = u ? Uw : Vw;
  const int hh = t & 63, dg = t >> 6;
  const size_t base = (size_t)k * DIM * HID + hc * 64 + hh;
  float am = 0.f;
  for (int i = 0; i < 256; ++i)
    am = fmaxf(am, fabsf(W[base + (size_t)(dg * 256 + i) * HID]));
  red[dg][hh] = am;
  __syncthreads();
  if (t < 64) {
    const float m = fmaxf(fmaxf(red[0][t], red[1][t]), fmaxf(red[2][t], red[3][t]));
    const int h = hc * 64 + t;
    const int c = (h >> 4) * 32 + u * 16 + (h & 15);
    swp[k * 1024 + c]  = m / 127.f;
    rswp[k * 1024 + c] = (m > 0.f) ? 127.f / m : 0.f;
  }
}

// ---------------- pack W -> Wq[col][d] int8 via LDS transpose (2048 blk: k16 x hc8 x dc16) ----
__global__ void pack_wq_kernel(const float* __restrict__ Vw,
                               const float* __restrict__ Uw,
                               const float* __restrict__ rswp,
                               signed char* __restrict__ Wq) {
  __shared__ __align__(16) signed char T[128][80];   // pad 80: <=2-way on i32x4 reads
  const int bid = blockIdx.x;
  const int k = bid >> 7, hc = (bid >> 4) & 7, dc = bid & 15;
  const int t = threadIdx.x;
  const int d0 = dc * 64, h0 = hc * 64;
  const int hh = t & 63;                 // fixed per thread
  const size_t base = (size_t)k * DIM * HID;
  #pragma unroll
  for (int u = 0; u < 2; ++u) {
    const float* W = u ? Uw : Vw;
    const int h = h0 + hh;
    const int cl = ((hh >> 4) << 5) + (u << 4) + (hh & 15);
    const float rs = rswp[k * 1024 + hc * 128 + cl];
    #pragma unroll
    for (int i = 0; i < 16; ++i) {
      const int dd = i * 4 + (t >> 6);
      T[cl][dd] = (signed char)q8(W[base + (size_t)(d0 + dd) * HID + h], rs);
    }
  }
  __syncthreads();
  #pragma unroll
  for (int j = 0; j < 2; ++j) {
    const int idx = j * 256 + t;
    const int cl = idx >> 2, dq = idx & 3;
    i32x4 val = *(const i32x4*)&T[cl][dq * 16];
    const size_t col = (size_t)k * 1024 + hc * 128 + cl;
    *(i32x4*)&Wq[col * DIM + d0 + dq * 16] = val;
  }
}

// ---------------- main GEMM (int8) + gated epilogue -> score partials ----------------
// 256x256 tile, BK=64 (64B rows), 8 waves (2M x 4N), mfma_i32_16x16x64_i8,
// 2-bit XOR swizzle, one barrier/K-tile, L2-aware map, 2 blocks/CU co-residency.
__global__ __launch_bounds__(512, 4) void gemm_scores_kernel(
    const signed char* __restrict__ xq, const signed char* __restrict__ Wq,
    const float* __restrict__ sx, const float* __restrict__ swp,
    const float* __restrict__ Vb, const float* __restrict__ Ub,
    const float* __restrict__ ww, float* __restrict__ part) {
  __shared__ __align__(16) signed char As[2][16384];   // 2 x 16 KB
  __shared__ __align__(16) signed char Bs[2][16384];
  const int bid = blockIdx.x;
  const int x8 = bid & 7;
  const int s  = (bid >> 3) & 31;
  const int w  = bid >> 8;
  const int mt = (x8 & 1) * 16 + (w & 1) * 8 + (s >> 2);   // 0..31
  const int ct = (x8 >> 1) * 16 + (w >> 1) * 4 + (s & 3);  // 0..63
  const int kh = ct >> 2, cb = ct & 3;
  const int tid = threadIdx.x;
  const int wv = tid >> 6, lane = tid & 63;
  const int wr = wv >> 2, wc = wv & 3;
  const int l15 = lane & 15, l4 = lane >> 4;

  const signed char* Ab = xq + (size_t)mt * 256 * DIM;
  const signed char* Bb = Wq + (size_t)ct * 256 * DIM;

  i32x4 acc[8][4];
  #pragma unroll
  for (int i = 0; i < 8; ++i)
    #pragma unroll
    for (int j = 0; j < 4; ++j) acc[i][j] = (i32x4){0, 0, 0, 0};

  auto stageA = [&](int t) {
    const int buf = t & 1, db = t << 6;
    #pragma unroll
    for (int p = 0; p < 2; ++p) {
      const int r = p * 128 + (tid >> 2);
      const int ksrc = ((tid & 3) * 16) ^ (((r >> 1) & 3) << 4);
      gload_lds16(Ab + (size_t)r * DIM + db + ksrc,
                  (char*)&As[buf][0] + p * 8192 + wv * 1024);
    }
  };
  auto stageB = [&](int t) {
    const int buf = t & 1, db = t << 6;
    #pragma unroll
    for (int p = 0; p < 2; ++p) {
      const int r = p * 128 + (tid >> 2);
      const int ksrc = ((tid & 3) * 16) ^ (((r >> 1) & 3) << 4);
      gload_lds16(Bb + (size_t)r * DIM + db + ksrc,
                  (char*)&Bs[buf][0] + p * 8192 + wv * 1024);
    }
  };

  const int swz = ((l15 >> 1) & 3) << 4;
  const int kb0 = (l4 * 16) ^ swz;
  const int aB0 = wr * 8192 + l15 * 64 + kb0;   // frag f: +f*1024
  const int bB0 = wc * 4096 + l15 * 64 + kb0;   // frag nf: +nf*1024

  i32x4 a[8], b[4];

  stageA(0); stageB(0); stageA(1); stageB(1);
  __syncthreads();

  for (int u = 0; u < 16; ++u) {
    const int buf = u & 1;
    const char* Abase = (const char*)&As[buf][0];
    const char* Bbase = (const char*)&Bs[buf][0];
    #pragma unroll
    for (int f = 0; f < 8; ++f) a[f] = *(const i32x4*)(Abase + aB0 + f * 1024);
    #pragma unroll
    for (int nf = 0; nf < 4; ++nf) b[nf] = *(const i32x4*)(Bbase + bB0 + nf * 1024);
    if (u < 15) { stageA(u + 1); stageB(u + 1); }
    __builtin_amdgcn_s_setprio(1);
    #pragma unroll
    for (int f = 0; f < 8; ++f)
      #pragma unroll
      for (int nf = 0; nf < 4; ++nf)
        acc[f][nf] = __builtin_amdgcn_mfma_i32_16x16x64_i8(a[f], b[nf], acc[f][nf], 0, 0, 0);
    __builtin_amdgcn_s_setprio(0);
    __syncthreads();
  }

  // ---- gated epilogue with dequant ----
  float partial[8][4];
  #pragma unroll
  for (int f = 0; f < 8; ++f)
    #pragma unroll
    for (int r = 0; r < 4; ++r) partial[f][r] = 0.f;

  float vb[2], ub[2], wwv[2], swv[2], swu[2];
  #pragma unroll
  for (int p = 0; p < 2; ++p) {
    const int hl = (cb * 8 + wc * 2 + p) * 16 + l15;
    vb[p]  = Vb[kh * HID + hl];
    ub[p]  = Ub[kh * HID + hl];
    wwv[p] = ww[kh * HID + hl];
    swv[p] = swp[ct * 256 + wc * 64 + (2 * p) * 16 + l15];
    swu[p] = swp[ct * 256 + wc * 64 + (2 * p + 1) * 16 + l15];
  }
  const int rbase = mt * 256 + wr * 128 + l4 * 4;
  #pragma unroll
  for (int f = 0; f < 8; ++f) {
    const float4 sx4 = *(const float4*)&sx[rbase + f * 16];
    const float sxr[4] = {sx4.x, sx4.y, sx4.z, sx4.w};
    #pragma unroll
    for (int p = 0; p < 2; ++p)
      #pragma unroll
      for (int r = 0; r < 4; ++r) {
        const float scv = (float)acc[f][2 * p][r] * (sxr[r] * swv[p]) + vb[p];
        const float scu = (float)acc[f][2 * p + 1][r] * (sxr[r] * swu[p]) + ub[p];
        const float e2 = __expf(2.f * scv);
        const float av = 1.f - 2.f / (e2 + 1.f);          // tanh
        const float au = 1.f / (1.f + __expf(-scu));      // sigmoid
        partial[f][r] += av * au * wwv[p];
      }
  }
  #pragma unroll
  for (int s2 = 1; s2 < 16; s2 <<= 1)
    #pragma unroll
    for (int f = 0; f < 8; ++f)
      #pragma unroll
      for (int r = 0; r < 4; ++r)
        partial[f][r] += __shfl_xor(partial[f][r], s2, 64);

  if (l15 == 0) {
    const int j = cb * 4 + wc;
    float* dst = part + ((size_t)j * NHEAD + kh) * N_PATCH;
    #pragma unroll
    for (int f = 0; f < 8; ++f)
      #pragma unroll
      for (int r = 0; r < 4; ++r)
        dst[rbase + f * 16 + r] = partial[f][r];
  }
}

// ---------------- scores + per-chunk softmax partials (128 blocks) ----------------
__global__ void scores_part_kernel(const float* __restrict__ part,
                                   float* __restrict__ scores,
                                   float* __restrict__ spart) {
  const int k = blockIdx.x >> 3, c = blockIdx.x & 7;
  const int t = threadIdx.x;
  __shared__ float shm[4], shs[4];
  float v[4];
  float mx = -1e30f;
  #pragma unroll
  for (int i = 0; i < 4; ++i) {
    const int n = c * 1024 + i * 256 + t;
    float s = 0.f;
    #pragma unroll
    for (int j = 0; j < 16; ++j) s += part[((size_t)j * NHEAD + k) * N_PATCH + n];
    v[i] = s;
    scores[(size_t)k * N_PATCH + n] = s;
    mx = fmaxf(mx, s);
  }
  #pragma unroll
  for (int sft = 32; sft; sft >>= 1) mx = fmaxf(mx, __shfl_xor(mx, sft, 64));
  const int wv = t >> 6;
  if ((t & 63) == 0) shm[wv] = mx;
  __syncthreads();
  mx = fmaxf(fmaxf(shm[0], shm[1]), fmaxf(shm[2], shm[3]));
  float sum = 0.f;
  #pragma unroll
  for (int i = 0; i < 4; ++i) sum += __expf(v[i] - mx);
  #pragma unroll
  for (int sft = 32; sft; sft >>= 1) sum += __shfl_xor(sum, sft, 64);
  if ((t & 63) == 0) shs[wv] = sum;
  __syncthreads();
  if (t == 0) {
    spart[(k * 8 + c) * 2]     = mx;
    spart[(k * 8 + c) * 2 + 1] = shs[0] + shs[1] + shs[2] + shs[3];
  }
}

// ---------------- fused: stats; w[n]=sum_k softmax; partial col-sums (int8 x + sx) ----
__global__ void weighted_part_kernel(const signed char* __restrict__ xq,
                                     const float* __restrict__ sx,
                                     const float* __restrict__ scores,
                                     const float* __restrict__ spart,
                                     float* __restrict__ wp1,
                                     float* __restrict__ wp2) {
  __shared__ float wsx[128], s2x[128];
  __shared__ float sm[16], srz[16];
  const int d = blockIdx.x * 256 + threadIdx.x;
  const int nc = blockIdx.y;
  if (threadIdx.x < 16) {
    const int k = threadIdx.x;
    float m = -1e30f;
    #pragma unroll
    for (int c = 0; c < 8; ++c) m = fmaxf(m, spart[(k * 8 + c) * 2]);
    float S = 0.f;
    #pragma unroll
    for (int c = 0; c < 8; ++c)
      S += spart[(k * 8 + c) * 2 + 1] * __expf(spart[(k * 8 + c) * 2] - m);
    sm[k] = m; srz[k] = 1.f / S;
  }
  __syncthreads();
  if (threadIdx.x < 128) {
    const int n = nc * 128 + threadIdx.x;
    float s = 0.f;
    #pragma unroll
    for (int k = 0; k < NHEAD; ++k)
      s += __expf(scores[(size_t)k * N_PATCH + n] - sm[k]) * srz[k];
    const float sxn = sx[n];
    wsx[threadIdx.x] = s * sxn;
    s2x[threadIdx.x] = sxn;
  }
  __syncthreads();
  float a1 = 0.f, a2 = 0.f;
  for (int i = 0; i < 128; ++i) {
    const float q = (float)xq[(size_t)(nc * 128 + i) * DIM + d];
    a1 += wsx[i] * q;
    a2 += s2x[i] * q;
  }
  wp1[nc * DIM + d] = a1;
  wp2[nc * DIM + d] = a2;
}

__global__ void reduce_vec_kernel(const float* __restrict__ wp1,
                                  const float* __restrict__ wp2,
                                  float* __restrict__ y1,
                                  float* __restrict__ mvec) {
  int d = blockIdx.x * 256 + threadIdx.x;
  float s1 = 0.f, s2 = 0.f;
  #pragma unroll
  for (int i = 0; i < 64; ++i) {
    s1 += wp1[i * DIM + d];
    s2 += wp2[i * DIM + d];
  }
  y1[d] = s1;
  mvec[d] = s2 * (1.f / (float)N_PATCH);
}

// ---------------- one-dispatch GEMV: in-block split-K (4 kc x 64 j) ----------------
__global__ void gemv_fused_kernel(const float* __restrict__ in,
                                  const float* __restrict__ W,
                                  const float* __restrict__ bias,
                                  const float* __restrict__ extra, float scale,
                                  int do_relu, float* __restrict__ out,
                                  int In, int Out) {
  __shared__ float red[4][64];
  const int jl = threadIdx.x & 63, kc = threadIdx.x >> 6;
  const int j = blockIdx.x * 64 + jl;
  const int chunk = In >> 2;
  const float* Wp = W + (size_t)(kc * chunk) * Out + j;
  const float* ip = in + kc * chunk;
  float acc = 0.f;
  #pragma unroll 4
  for (int d = 0; d < chunk; ++d) acc += ip[d] * Wp[(size_t)d * Out];
  if (kc) red[kc][jl] = acc;
  __syncthreads();
  if (kc == 0) {
    float v = bias[j] + acc + red[1][jl] + red[2][jl] + red[3][jl];
    if (extra) v += extra[j];
    v *= scale;
    if (do_relu) v = fmaxf(v, 0.f);
    out[j] = v;
  }
}

// ---------------- fused: c3 = relu(c2@cW3+cb3); logits; softmax ----------------
__global__ void c3_final_kernel(const float* __restrict__ c2,
                                const float* __restrict__ W3,
                                const float* __restrict__ b3,
                                const float* __restrict__ W4,
                                const float* __restrict__ b4,
                                float* __restrict__ out) {
  __shared__ float c3s[256];
  __shared__ float logits[9];
  const int t = threadIdx.x;
  float acc = b3[t];
  #pragma unroll 4
  for (int d = 0; d < 512; ++d) acc += c2[d] * W3[(size_t)d * 256 + t];
  c3s[t] = fmaxf(acc, 0.f);
  __syncthreads();
  if (t < 9) {
    float l = b4[t];
    for (int d = 0; d < 256; ++d) l += c3s[d] * W4[d * 9 + t];
    logits[t] = l;
  }
  __syncthreads();
  if (t == 0) {
    float mx = logits[0];
    for (int j = 1; j < 9; ++j) mx = fmaxf(mx, logits[j]);
    float e[9], s = 0.f;
    for (int j = 0; j < 9; ++j) { e[j] = expf(logits[j] - mx); s += e[j]; }
    for (int j = 0; j < 9; ++j) out[j] = e[j] / s;
  }
}

extern "C" void kernel_launch(void* const* d_in, const int* in_sizes, int n_in,
                              void* d_out, int out_size, void* d_ws, size_t ws_size,
                              hipStream_t stream) {
  (void)in_sizes; (void)n_in; (void)out_size; (void)ws_size;
  const float* x   = (const float*)d_in[0];
  const float* Vw  = (const float*)d_in[1];
  const float* Vb  = (const float*)d_in[2];
  const float* Uw  = (const float*)d_in[3];
  const float* Ub  = (const float*)d_in[4];
  const float* ww  = (const float*)d_in[5];
  // d_in[6] = wb: constant per head -> softmax invariant -> unused
  const float* pW1 = (const float*)d_in[7];
  const float* pb1 = (const float*)d_in[8];
  const float* pW2 = (const float*)d_in[9];
  const float* pb2 = (const float*)d_in[10];
  const float* cW1 = (const float*)d_in[11];
  const float* cb1 = (const float*)d_in[12];
  const float* cW2 = (const float*)d_in[13];
  const float* cb2 = (const float*)d_in[14];
  const float* cW3 = (const float*)d_in[15];
  const float* cb3 = (const float*)d_in[16];
  const float* cW4 = (const float*)d_in[17];
  const float* cb4 = (const float*)d_in[18];
  float* out = (float*)d_out;

  char* ws = (char*)d_ws;
  size_t o = 0;
  auto alloc = [&](size_t bytes) -> char* {
    char* p = ws + o;
    o += (bytes + 255) & ~(size_t)255;
    return p;
  };
  signed char* xq = (signed char*)alloc((size_t)N_PATCH * DIM);       // 8 MB
  signed char* Wq = (signed char*)alloc((size_t)NHEAD * 1024 * DIM);  // 16 MB
  float* sx    = (float*)alloc(N_PATCH * 4);
  float* swp   = (float*)alloc(NHEAD * 1024 * 4);
  float* rswp  = (float*)alloc(NHEAD * 1024 * 4);
  float* part  = (float*)alloc((size_t)16 * NHEAD * N_PATCH * 4);     // 8 MB
  float* scores= (float*)alloc((size_t)NHEAD * N_PATCH * 4);
  float* spart = (float*)alloc(NHEAD * 8 * 2 * 4);
  float* wp1   = (float*)alloc(64 * DIM * 4);
  float* wp2   = (float*)alloc(64 * DIM * 4);
  float* y1    = (float*)alloc(DIM * 4);
  float* mvec  = (float*)alloc(DIM * 4);
  float* h1    = (float*)alloc(HID * 4);
  float* aggr  = (float*)alloc(DIM * 4);
  float* c1    = (float*)alloc(1024 * 4);
  float* c2    = (float*)alloc(512 * 4);

  prep1_kernel<<<2304, 256, 0, stream>>>(x, xq, sx, Vw, Uw, swp, rswp);
  pack_wq_kernel<<<2048, 256, 0, stream>>>(Vw, Uw, rswp, Wq);
  gemm_scores_kernel<<<2048, 512, 0, stream>>>(xq, Wq, sx, swp, Vb, Ub, ww, part);
  scores_part_kernel<<<128, 256, 0, stream>>>(part, scores, spart);
  weighted_part_kernel<<<dim3(4, 64), 256, 0, stream>>>(xq, sx, scores, spart, wp1, wp2);
  reduce_vec_kernel<<<4, 256, 0, stream>>>(wp1, wp2, y1, mvec);
  gemv_fused_kernel<<<8, 256, 0, stream>>>(mvec, pW1, pb1, nullptr, 1.f, 1, h1, DIM, HID);
  gemv_fused_kernel<<<16, 256, 0, stream>>>(h1, pW2, pb2, y1, 1.f / 17.f, 0, aggr, HID, DIM);
  gemv_fused_kernel<<<16, 256, 0, stream>>>(aggr, cW1, cb1, nullptr, 1.f, 1, c1, 1024, 1024);
  gemv_fused_kernel<<<8, 256, 0, stream>>>(c1, cW2, cb2, nullptr, 1.f, 1, c2, 1024, 512);
  c3_final_kernel<<<1, 256, 0, stream>>>(c2, cW3, cb3, cW4, cb4, out);
}

// Round 14
// 388.069 us; speedup vs baseline: 3.7936x; 3.7936x over previous
//
#include <hip/hip_runtime.h>
#include <stdint.h>

#define N_PATCH 8192
#define DIM     1024
#define HID     512
#define NHEAD   16

using i32x4 = __attribute__((ext_vector_type(4))) int;

__device__ __forceinline__ void gload_lds16(const void* g, void* l) {
  __builtin_amdgcn_global_load_lds(
      reinterpret_cast<const __attribute__((address_space(1))) void*>(
          reinterpret_cast<uintptr_t>(g)),
      reinterpret_cast<__attribute__((address_space(3))) void*>(
          reinterpret_cast<uintptr_t>(l)),
      16, 0, 0);
}

__device__ __forceinline__ int q8(float v, float rs) {
  int q = (int)rintf(v * rs);
  return q > 127 ? 127 : (q < -127 ? -127 : q);
}

// ---------------- prep1: quantize x per-row (bid<2048) + W column amax (bid>=2048, 256 blk) ----
__global__ void prep1_kernel(const float* __restrict__ x,
                             signed char* __restrict__ xq, float* __restrict__ sx,
                             const float* __restrict__ Vw, const float* __restrict__ Uw,
                             float* __restrict__ swp, float* __restrict__ rswp) {
  __shared__ __align__(16) float red4[16][16][4];   // 4 KB
  const int bid = blockIdx.x;
  const int t = threadIdx.x;
  if (bid < 2048) {            // ---- x: one wave per row, 4 rows/block ----
    const int row = bid * 4 + (t >> 6);
    const int lane = t & 63;
    const float* xr = x + (size_t)row * DIM;
    float4 v[4];
    float am = 0.f;
    #pragma unroll
    for (int j = 0; j < 4; ++j) {
      v[j] = *(const float4*)&xr[j * 256 + lane * 4];
      am = fmaxf(am, fmaxf(fmaxf(fabsf(v[j].x), fabsf(v[j].y)),
                           fmaxf(fabsf(v[j].z), fabsf(v[j].w))));
    }
    #pragma unroll
    for (int s = 32; s; s >>= 1) am = fmaxf(am, __shfl_xor(am, s, 64));
    const float rs = (am > 0.f) ? 127.f / am : 0.f;
    #pragma unroll
    for (int j = 0; j < 4; ++j) {
      int b = (q8(v[j].x, rs) & 255) | ((q8(v[j].y, rs) & 255) << 8) |
              ((q8(v[j].z, rs) & 255) << 16) | ((q8(v[j].w, rs) & 255) << 24);
      ((int*)xq)[row * 256 + j * 64 + lane] = b;
    }
    if (lane == 0) sx[row] = am / 127.f;
    return;
  }
  // ---- W column amax: 256 blocks = u(2) x k(16) x hc(8), 64 cols each ----
  // float4 over h (coalesced 256B segments), 16 d-segments in parallel.
  const int b2 = bid - 2048;
  const int u = b2 >> 7, k = (b2 >> 3) & 15, hc = b2 & 7;
  const float* W = u ? Uw : Vw;
  const int h4 = t & 15, dseg = t >> 4;   // 16 h-groups x 16 d-segs
  const size_t base = (size_t)k * DIM * HID + hc * 64 + h4 * 4;
  float4 am4 = {0.f, 0.f, 0.f, 0.f};
  for (int i = 0; i < 64; ++i) {
    float4 v = *(const float4*)&W[base + (size_t)(dseg * 64 + i) * HID];
    am4.x = fmaxf(am4.x, fabsf(v.x));
    am4.y = fmaxf(am4.y, fabsf(v.y));
    am4.z = fmaxf(am4.z, fabsf(v.z));
    am4.w = fmaxf(am4.w, fabsf(v.w));
  }
  *(float4*)&red4[dseg][h4][0] = am4;
  __syncthreads();
  if (t < 64) {
    float m = 0.f;
    #pragma unroll
    for (int ds = 0; ds < 16; ++ds) m = fmaxf(m, red4[ds][t >> 2][t & 3]);
    const int h = hc * 64 + t;
    const int c = (h >> 4) * 32 + u * 16 + (h & 15);
    swp[k * 1024 + c]  = m / 127.f;
    rswp[k * 1024 + c] = (m > 0.f) ? 127.f / m : 0.f;
  }
}

// ---------------- pack W -> Wq[col][d] int8 via LDS transpose (2048 blk: k16 x hc8 x dc16) ----
__global__ void pack_wq_kernel(const float* __restrict__ Vw,
                               const float* __restrict__ Uw,
                               const float* __restrict__ rswp,
                               signed char* __restrict__ Wq) {
  __shared__ __align__(16) signed char T[128][80];   // pad 80: <=2-way on i32x4 reads
  const int bid = blockIdx.x;
  const int k = bid >> 7, hc = (bid >> 4) & 7, dc = bid & 15;
  const int t = threadIdx.x;
  const int d0 = dc * 64, h0 = hc * 64;
  const int hh = t & 63;                 // fixed per thread
  const size_t base = (size_t)k * DIM * HID;
  #pragma unroll
  for (int u = 0; u < 2; ++u) {
    const float* W = u ? Uw : Vw;
    const int h = h0 + hh;
    const int cl = ((hh >> 4) << 5) + (u << 4) + (hh & 15);
    const float rs = rswp[k * 1024 + hc * 128 + cl];
    #pragma unroll
    for (int i = 0; i < 16; ++i) {
      const int dd = i * 4 + (t >> 6);
      T[cl][dd] = (signed char)q8(W[base + (size_t)(d0 + dd) * HID + h], rs);
    }
  }
  __syncthreads();
  #pragma unroll
  for (int j = 0; j < 2; ++j) {
    const int idx = j * 256 + t;
    const int cl = idx >> 2, dq = idx & 3;
    i32x4 val = *(const i32x4*)&T[cl][dq * 16];
    const size_t col = (size_t)k * 1024 + hc * 128 + cl;
    *(i32x4*)&Wq[col * DIM + d0 + dq * 16] = val;
  }
}

// ---------------- main GEMM (int8) + gated epilogue -> score partials ----------------
// 256x256 tile, BK=64 (64B rows), 8 waves (2M x 4N), mfma_i32_16x16x64_i8,
// 2-bit XOR swizzle, one barrier/K-tile (wave-skew overlap), L2-aware map.
// NOTE: launch_bounds min-waves MUST stay 1 — acc[8][4] i32x4 = 128 regs;
// (512,4) forces a 128-reg cap -> full accumulator spill (r13: 1247 us).
__global__ __launch_bounds__(512, 1) void gemm_scores_kernel(
    const signed char* __restrict__ xq, const signed char* __restrict__ Wq,
    const float* __restrict__ sx, const float* __restrict__ swp,
    const float* __restrict__ Vb, const float* __restrict__ Ub,
    const float* __restrict__ ww, float* __restrict__ part) {
  __shared__ __align__(16) signed char As[2][16384];   // 2 x 16 KB
  __shared__ __align__(16) signed char Bs[2][16384];
  const int bid = blockIdx.x;
  const int x8 = bid & 7;
  const int s  = (bid >> 3) & 31;
  const int w  = bid >> 8;
  const int mt = (x8 & 1) * 16 + (w & 1) * 8 + (s >> 2);   // 0..31
  const int ct = (x8 >> 1) * 16 + (w >> 1) * 4 + (s & 3);  // 0..63
  const int kh = ct >> 2, cb = ct & 3;
  const int tid = threadIdx.x;
  const int wv = tid >> 6, lane = tid & 63;
  const int wr = wv >> 2, wc = wv & 3;
  const int l15 = lane & 15, l4 = lane >> 4;

  const signed char* Ab = xq + (size_t)mt * 256 * DIM;
  const signed char* Bb = Wq + (size_t)ct * 256 * DIM;

  i32x4 acc[8][4];
  #pragma unroll
  for (int i = 0; i < 8; ++i)
    #pragma unroll
    for (int j = 0; j < 4; ++j) acc[i][j] = (i32x4){0, 0, 0, 0};

  auto stageA = [&](int t) {
    const int buf = t & 1, db = t << 6;
    #pragma unroll
    for (int p = 0; p < 2; ++p) {
      const int r = p * 128 + (tid >> 2);
      const int ksrc = ((tid & 3) * 16) ^ (((r >> 1) & 3) << 4);
      gload_lds16(Ab + (size_t)r * DIM + db + ksrc,
                  (char*)&As[buf][0] + p * 8192 + wv * 1024);
    }
  };
  auto stageB = [&](int t) {
    const int buf = t & 1, db = t << 6;
    #pragma unroll
    for (int p = 0; p < 2; ++p) {
      const int r = p * 128 + (tid >> 2);
      const int ksrc = ((tid & 3) * 16) ^ (((r >> 1) & 3) << 4);
      gload_lds16(Bb + (size_t)r * DIM + db + ksrc,
                  (char*)&Bs[buf][0] + p * 8192 + wv * 1024);
    }
  };

  const int swz = ((l15 >> 1) & 3) << 4;
  const int kb0 = (l4 * 16) ^ swz;
  const int aB0 = wr * 8192 + l15 * 64 + kb0;   // frag f: +f*1024
  const int bB0 = wc * 4096 + l15 * 64 + kb0;   // frag nf: +nf*1024

  i32x4 a[8], b[4];

  stageA(0); stageB(0); stageA(1); stageB(1);
  __syncthreads();

  for (int u = 0; u < 16; ++u) {
    const int buf = u & 1;
    const char* Abase = (const char*)&As[buf][0];
    const char* Bbase = (const char*)&Bs[buf][0];
    #pragma unroll
    for (int f = 0; f < 8; ++f) a[f] = *(const i32x4*)(Abase + aB0 + f * 1024);
    #pragma unroll
    for (int nf = 0; nf < 4; ++nf) b[nf] = *(const i32x4*)(Bbase + bB0 + nf * 1024);
    if (u < 15) { stageA(u + 1); stageB(u + 1); }
    __builtin_amdgcn_s_setprio(1);
    #pragma unroll
    for (int f = 0; f < 8; ++f)
      #pragma unroll
      for (int nf = 0; nf < 4; ++nf)
        acc[f][nf] = __builtin_amdgcn_mfma_i32_16x16x64_i8(a[f], b[nf], acc[f][nf], 0, 0, 0);
    __builtin_amdgcn_s_setprio(0);
    __syncthreads();
  }

  // ---- gated epilogue with dequant ----
  float partial[8][4];
  #pragma unroll
  for (int f = 0; f < 8; ++f)
    #pragma unroll
    for (int r = 0; r < 4; ++r) partial[f][r] = 0.f;

  float vb[2], ub[2], wwv[2], swv[2], swu[2];
  #pragma unroll
  for (int p = 0; p < 2; ++p) {
    const int hl = (cb * 8 + wc * 2 + p) * 16 + l15;
    vb[p]  = Vb[kh * HID + hl];
    ub[p]  = Ub[kh * HID + hl];
    wwv[p] = ww[kh * HID + hl];
    swv[p] = swp[ct * 256 + wc * 64 + (2 * p) * 16 + l15];
    swu[p] = swp[ct * 256 + wc * 64 + (2 * p + 1) * 16 + l15];
  }
  const int rbase = mt * 256 + wr * 128 + l4 * 4;
  #pragma unroll
  for (int f = 0; f < 8; ++f) {
    const float4 sx4 = *(const float4*)&sx[rbase + f * 16];
    const float sxr[4] = {sx4.x, sx4.y, sx4.z, sx4.w};
    #pragma unroll
    for (int p = 0; p < 2; ++p)
      #pragma unroll
      for (int r = 0; r < 4; ++r) {
        const float scv = (float)acc[f][2 * p][r] * (sxr[r] * swv[p]) + vb[p];
        const float scu = (float)acc[f][2 * p + 1][r] * (sxr[r] * swu[p]) + ub[p];
        const float e2 = __expf(2.f * scv);
        const float av = 1.f - 2.f / (e2 + 1.f);          // tanh
        const float au = 1.f / (1.f + __expf(-scu));      // sigmoid
        partial[f][r] += av * au * wwv[p];
      }
  }
  #pragma unroll
  for (int s2 = 1; s2 < 16; s2 <<= 1)
    #pragma unroll
    for (int f = 0; f < 8; ++f)
      #pragma unroll
      for (int r = 0; r < 4; ++r)
        partial[f][r] += __shfl_xor(partial[f][r], s2, 64);

  if (l15 == 0) {
    const int j = cb * 4 + wc;
    float* dst = part + ((size_t)j * NHEAD + kh) * N_PATCH;
    #pragma unroll
    for (int f = 0; f < 8; ++f)
      #pragma unroll
      for (int r = 0; r < 4; ++r)
        dst[rbase + f * 16 + r] = partial[f][r];
  }
}

// ---------------- scores + per-chunk softmax partials (128 blocks) ----------------
__global__ void scores_part_kernel(const float* __restrict__ part,
                                   float* __restrict__ scores,
                                   float* __restrict__ spart) {
  const int k = blockIdx.x >> 3, c = blockIdx.x & 7;
  const int t = threadIdx.x;
  __shared__ float shm[4], shs[4];
  float v[4];
  float mx = -1e30f;
  #pragma unroll
  for (int i = 0; i < 4; ++i) {
    const int n = c * 1024 + i * 256 + t;
    float s = 0.f;
    #pragma unroll
    for (int j = 0; j < 16; ++j) s += part[((size_t)j * NHEAD + k) * N_PATCH + n];
    v[i] = s;
    scores[(size_t)k * N_PATCH + n] = s;
    mx = fmaxf(mx, s);
  }
  #pragma unroll
  for (int sft = 32; sft; sft >>= 1) mx = fmaxf(mx, __shfl_xor(mx, sft, 64));
  const int wv = t >> 6;
  if ((t & 63) == 0) shm[wv] = mx;
  __syncthreads();
  mx = fmaxf(fmaxf(shm[0], shm[1]), fmaxf(shm[2], shm[3]));
  float sum = 0.f;
  #pragma unroll
  for (int i = 0; i < 4; ++i) sum += __expf(v[i] - mx);
  #pragma unroll
  for (int sft = 32; sft; sft >>= 1) sum += __shfl_xor(sum, sft, 64);
  if ((t & 63) == 0) shs[wv] = sum;
  __syncthreads();
  if (t == 0) {
    spart[(k * 8 + c) * 2]     = mx;
    spart[(k * 8 + c) * 2 + 1] = shs[0] + shs[1] + shs[2] + shs[3];
  }
}

// ---------------- fused: stats; w[n]=sum_k softmax; partial col-sums (int8 x + sx) ----
__global__ void weighted_part_kernel(const signed char* __restrict__ xq,
                                     const float* __restrict__ sx,
                                     const float* __restrict__ scores,
                                     const float* __restrict__ spart,
                                     float* __restrict__ wp1,
                                     float* __restrict__ wp2) {
  __shared__ float wsx[128], s2x[128];
  __shared__ float sm[16], srz[16];
  const int d = blockIdx.x * 256 + threadIdx.x;
  const int nc = blockIdx.y;
  if (threadIdx.x < 16) {
    const int k = threadIdx.x;
    float m = -1e30f;
    #pragma unroll
    for (int c = 0; c < 8; ++c) m = fmaxf(m, spart[(k * 8 + c) * 2]);
    float S = 0.f;
    #pragma unroll
    for (int c = 0; c < 8; ++c)
      S += spart[(k * 8 + c) * 2 + 1] * __expf(spart[(k * 8 + c) * 2] - m);
    sm[k] = m; srz[k] = 1.f / S;
  }
  __syncthreads();
  if (threadIdx.x < 128) {
    const int n = nc * 128 + threadIdx.x;
    float s = 0.f;
    #pragma unroll
    for (int k = 0; k < NHEAD; ++k)
      s += __expf(scores[(size_t)k * N_PATCH + n] - sm[k]) * srz[k];
    const float sxn = sx[n];
    wsx[threadIdx.x] = s * sxn;
    s2x[threadIdx.x] = sxn;
  }
  __syncthreads();
  float a1 = 0.f, a2 = 0.f;
  for (int i = 0; i < 128; ++i) {
    const float q = (float)xq[(size_t)(nc * 128 + i) * DIM + d];
    a1 += wsx[i] * q;
    a2 += s2x[i] * q;
  }
  wp1[nc * DIM + d] = a1;
  wp2[nc * DIM + d] = a2;
}

__global__ void reduce_vec_kernel(const float* __restrict__ wp1,
                                  const float* __restrict__ wp2,
                                  float* __restrict__ y1,
                                  float* __restrict__ mvec) {
  int d = blockIdx.x * 256 + threadIdx.x;
  float s1 = 0.f, s2 = 0.f;
  #pragma unroll
  for (int i = 0; i < 64; ++i) {
    s1 += wp1[i * DIM + d];
    s2 += wp2[i * DIM + d];
  }
  y1[d] = s1;
  mvec[d] = s2 * (1.f / (float)N_PATCH);
}

// ---------------- one-dispatch GEMV: in-block split-K (4 kc x 64 j) ----------------
__global__ void gemv_fused_kernel(const float* __restrict__ in,
                                  const float* __restrict__ W,
                                  const float* __restrict__ bias,
                                  const float* __restrict__ extra, float scale,
                                  int do_relu, float* __restrict__ out,
                                  int In, int Out) {
  __shared__ float red[4][64];
  const int jl = threadIdx.x & 63, kc = threadIdx.x >> 6;
  const int j = blockIdx.x * 64 + jl;
  const int chunk = In >> 2;
  const float* Wp = W + (size_t)(kc * chunk) * Out + j;
  const float* ip = in + kc * chunk;
  float acc = 0.f;
  #pragma unroll 4
  for (int d = 0; d < chunk; ++d) acc += ip[d] * Wp[(size_t)d * Out];
  if (kc) red[kc][jl] = acc;
  __syncthreads();
  if (kc == 0) {
    float v = bias[j] + acc + red[1][jl] + red[2][jl] + red[3][jl];
    if (extra) v += extra[j];
    v *= scale;
    if (do_relu) v = fmaxf(v, 0.f);
    out[j] = v;
  }
}

// ---------------- fused: c3 = relu(c2@cW3+cb3); logits; softmax ----------------
__global__ void c3_final_kernel(const float* __restrict__ c2,
                                const float* __restrict__ W3,
                                const float* __restrict__ b3,
                                const float* __restrict__ W4,
                                const float* __restrict__ b4,
                                float* __restrict__ out) {
  __shared__ float c3s[256];
  __shared__ float logits[9];
  const int t = threadIdx.x;
  float acc = b3[t];
  #pragma unroll 4
  for (int d = 0; d < 512; ++d) acc += c2[d] * W3[(size_t)d * 256 + t];
  c3s[t] = fmaxf(acc, 0.f);
  __syncthreads();
  if (t < 9) {
    float l = b4[t];
    for (int d = 0; d < 256; ++d) l += c3s[d] * W4[d * 9 + t];
    logits[t] = l;
  }
  __syncthreads();
  if (t == 0) {
    float mx = logits[0];
    for (int j = 1; j < 9; ++j) mx = fmaxf(mx, logits[j]);
    float e[9], s = 0.f;
    for (int j = 0; j < 9; ++j) { e[j] = expf(logits[j] - mx); s += e[j]; }
    for (int j = 0; j < 9; ++j) out[j] = e[j] / s;
  }
}

extern "C" void kernel_launch(void* const* d_in, const int* in_sizes, int n_in,
                              void* d_out, int out_size, void* d_ws, size_t ws_size,
                              hipStream_t stream) {
  (void)in_sizes; (void)n_in; (void)out_size; (void)ws_size;
  const float* x   = (const float*)d_in[0];
  const float* Vw  = (const float*)d_in[1];
  const float* Vb  = (const float*)d_in[2];
  const float* Uw  = (const float*)d_in[3];
  const float* Ub  = (const float*)d_in[4];
  const float* ww  = (const float*)d_in[5];
  // d_in[6] = wb: constant per head -> softmax invariant -> unused
  const float* pW1 = (const float*)d_in[7];
  const float* pb1 = (const float*)d_in[8];
  const float* pW2 = (const float*)d_in[9];
  const float* pb2 = (const float*)d_in[10];
  const float* cW1 = (const float*)d_in[11];
  const float* cb1 = (const float*)d_in[12];
  const float* cW2 = (const float*)d_in[13];
  const float* cb2 = (const float*)d_in[14];
  const float* cW3 = (const float*)d_in[15];
  const float* cb3 = (const float*)d_in[16];
  const float* cW4 = (const float*)d_in[17];
  const float* cb4 = (const float*)d_in[18];
  float* out = (float*)d_out;

  char* ws = (char*)d_ws;
  size_t o = 0;
  auto alloc = [&](size_t bytes) -> char* {
    char* p = ws + o;
    o += (bytes + 255) & ~(size_t)255;
    return p;
  };
  signed char* xq = (signed char*)alloc((size_t)N_PATCH * DIM);       // 8 MB
  signed char* Wq = (signed char*)alloc((size_t)NHEAD * 1024 * DIM);  // 16 MB
  float* sx    = (float*)alloc(N_PATCH * 4);
  float* swp   = (float*)alloc(NHEAD * 1024 * 4);
  float* rswp  = (float*)alloc(NHEAD * 1024 * 4);
  float* part  = (float*)alloc((size_t)16 * NHEAD * N_PATCH * 4);     // 8 MB
  float* scores= (float*)alloc((size_t)NHEAD * N_PATCH * 4);
  float* spart = (float*)alloc(NHEAD * 8 * 2 * 4);
  float* wp1   = (float*)alloc(64 * DIM * 4);
  float* wp2   = (float*)alloc(64 * DIM * 4);
  float* y1    = (float*)alloc(DIM * 4);
  float* mvec  = (float*)alloc(DIM * 4);
  float* h1    = (float*)alloc(HID * 4);
  float* aggr  = (float*)alloc(DIM * 4);
  float* c1    = (float*)alloc(1024 * 4);
  float* c2    = (float*)alloc(512 * 4);

  prep1_kernel<<<2304, 256, 0, stream>>>(x, xq, sx, Vw, Uw, swp, rswp);
  pack_wq_kernel<<<2048, 256, 0, stream>>>(Vw, Uw, rswp, Wq);
  gemm_scores_kernel<<<2048, 512, 0, stream>>>(xq, Wq, sx, swp, Vb, Ub, ww, part);
  scores_part_kernel<<<128, 256, 0, stream>>>(part, scores, spart);
  weighted_part_kernel<<<dim3(4, 64), 256, 0, stream>>>(xq, sx, scores, spart, wp1, wp2);
  reduce_vec_kernel<<<4, 256, 0, stream>>>(wp1, wp2, y1, mvec);
  gemv_fused_kernel<<<8, 256, 0, stream>>>(mvec, pW1, pb1, nullptr, 1.f, 1, h1, DIM, HID);
  gemv_fused_kernel<<<16, 256, 0, stream>>>(h1, pW2, pb2, y1, 1.f / 17.f, 0, aggr, HID, DIM);
  gemv_fused_kernel<<<16, 256, 0, stream>>>(aggr, cW1, cb1, nullptr, 1.f, 1, c1, 1024, 1024);
  gemv_fused_kernel<<<8, 256, 0, stream>>>(c1, cW2, cb2, nullptr, 1.f, 1, c2, 1024, 512);
  c3_final_kernel<<<1, 256, 0, stream>>>(c2, cW3, cb3, cW4, cb4, out);
}

// Round 15
// 384.179 us; speedup vs baseline: 3.8320x; 1.0101x over previous
//
#include <hip/hip_runtime.h>
#include <stdint.h>

#define N_PATCH 8192
#define DIM     1024
#define HID     512
#define NHEAD   16

using i32x4 = __attribute__((ext_vector_type(4))) int;

__device__ __forceinline__ void gload_lds16(const void* g, void* l) {
  __builtin_amdgcn_global_load_lds(
      reinterpret_cast<const __attribute__((address_space(1))) void*>(
          reinterpret_cast<uintptr_t>(g)),
      reinterpret_cast<__attribute__((address_space(3))) void*>(
          reinterpret_cast<uintptr_t>(l)),
      16, 0, 0);
}

__device__ __forceinline__ int q8(float v, float rs) {
  int q = (int)rintf(v * rs);
  return q > 127 ? 127 : (q < -127 ? -127 : q);
}

// ---------------- prep1: quantize x per-row (bid<2048) + W column amax (bid>=2048, 256 blk) ----
__global__ void prep1_kernel(const float* __restrict__ x,
                             signed char* __restrict__ xq, float* __restrict__ sx,
                             const float* __restrict__ Vw, const float* __restrict__ Uw,
                             float* __restrict__ swp, float* __restrict__ rswp) {
  __shared__ __align__(16) float red4[16][16][4];   // 4 KB
  const int bid = blockIdx.x;
  const int t = threadIdx.x;
  if (bid < 2048) {            // ---- x: one wave per row, 4 rows/block ----
    const int row = bid * 4 + (t >> 6);
    const int lane = t & 63;
    const float* xr = x + (size_t)row * DIM;
    float4 v[4];
    float am = 0.f;
    #pragma unroll
    for (int j = 0; j < 4; ++j) {
      v[j] = *(const float4*)&xr[j * 256 + lane * 4];
      am = fmaxf(am, fmaxf(fmaxf(fabsf(v[j].x), fabsf(v[j].y)),
                           fmaxf(fabsf(v[j].z), fabsf(v[j].w))));
    }
    #pragma unroll
    for (int s = 32; s; s >>= 1) am = fmaxf(am, __shfl_xor(am, s, 64));
    const float rs = (am > 0.f) ? 127.f / am : 0.f;
    #pragma unroll
    for (int j = 0; j < 4; ++j) {
      int b = (q8(v[j].x, rs) & 255) | ((q8(v[j].y, rs) & 255) << 8) |
              ((q8(v[j].z, rs) & 255) << 16) | ((q8(v[j].w, rs) & 255) << 24);
      ((int*)xq)[row * 256 + j * 64 + lane] = b;
    }
    if (lane == 0) sx[row] = am / 127.f;
    return;
  }
  // ---- W column amax: 256 blocks = u(2) x k(16) x hc(8), 64 cols each ----
  const int b2 = bid - 2048;
  const int u = b2 >> 7, k = (b2 >> 3) & 15, hc = b2 & 7;
  const float* W = u ? Uw : Vw;
  const int h4 = t & 15, dseg = t >> 4;   // 16 h-groups x 16 d-segs
  const size_t base = (size_t)k * DIM * HID + hc * 64 + h4 * 4;
  float4 am4 = {0.f, 0.f, 0.f, 0.f};
  for (int i = 0; i < 64; ++i) {
    float4 v = *(const float4*)&W[base + (size_t)(dseg * 64 + i) * HID];
    am4.x = fmaxf(am4.x, fabsf(v.x));
    am4.y = fmaxf(am4.y, fabsf(v.y));
    am4.z = fmaxf(am4.z, fabsf(v.z));
    am4.w = fmaxf(am4.w, fabsf(v.w));
  }
  *(float4*)&red4[dseg][h4][0] = am4;
  __syncthreads();
  if (t < 64) {
    float m = 0.f;
    #pragma unroll
    for (int ds = 0; ds < 16; ++ds) m = fmaxf(m, red4[ds][t >> 2][t & 3]);
    const int h = hc * 64 + t;
    const int c = (h >> 4) * 32 + u * 16 + (h & 15);
    swp[k * 1024 + c]  = m / 127.f;
    rswp[k * 1024 + c] = (m > 0.f) ? 127.f / m : 0.f;
  }
}

// ---------------- pack W -> Wq[col][d] int8 via LDS transpose (2048 blk: k16 x hc8 x dc16) ----
__global__ void pack_wq_kernel(const float* __restrict__ Vw,
                               const float* __restrict__ Uw,
                               const float* __restrict__ rswp,
                               signed char* __restrict__ Wq) {
  __shared__ __align__(16) signed char T[128][80];   // pad 80: <=2-way on i32x4 reads
  const int bid = blockIdx.x;
  const int k = bid >> 7, hc = (bid >> 4) & 7, dc = bid & 15;
  const int t = threadIdx.x;
  const int d0 = dc * 64, h0 = hc * 64;
  const int hh = t & 63;                 // fixed per thread
  const size_t base = (size_t)k * DIM * HID;
  #pragma unroll
  for (int u = 0; u < 2; ++u) {
    const float* W = u ? Uw : Vw;
    const int h = h0 + hh;
    const int cl = ((hh >> 4) << 5) + (u << 4) + (hh & 15);
    const float rs = rswp[k * 1024 + hc * 128 + cl];
    #pragma unroll
    for (int i = 0; i < 16; ++i) {
      const int dd = i * 4 + (t >> 6);
      T[cl][dd] = (signed char)q8(W[base + (size_t)(d0 + dd) * HID + h], rs);
    }
  }
  __syncthreads();
  #pragma unroll
  for (int j = 0; j < 2; ++j) {
    const int idx = j * 256 + t;
    const int cl = idx >> 2, dq = idx & 3;
    i32x4 val = *(const i32x4*)&T[cl][dq * 16];
    const size_t col = (size_t)k * 1024 + hc * 128 + cl;
    *(i32x4*)&Wq[col * DIM + d0 + dq * 16] = val;
  }
}

// ---------------- main GEMM (int8) + gated epilogue -> score partials ----------------
// 256x256 tile, BK=128 bytes (K=128 per tile, 8 tiles), 8 waves (2M x 4N),
// mfma_i32_16x16x64_i8 x2 k-halves, 3-bit XOR swizzle on 128B rows,
// ONE barrier per K-tile (8 total), L2-aware block map.
// launch_bounds min-waves stays 1: acc=128 AGPR + ~150 VGPR (r13 spill lesson).
__global__ __launch_bounds__(512, 1) void gemm_scores_kernel(
    const signed char* __restrict__ xq, const signed char* __restrict__ Wq,
    const float* __restrict__ sx, const float* __restrict__ swp,
    const float* __restrict__ Vb, const float* __restrict__ Ub,
    const float* __restrict__ ww, float* __restrict__ part) {
  __shared__ __align__(16) signed char As[2][32768];   // 2 x 32 KB
  __shared__ __align__(16) signed char Bs[2][32768];
  const int bid = blockIdx.x;
  const int x8 = bid & 7;
  const int s  = (bid >> 3) & 31;
  const int w  = bid >> 8;
  const int mt = (x8 & 1) * 16 + (w & 1) * 8 + (s >> 2);   // 0..31
  const int ct = (x8 >> 1) * 16 + (w >> 1) * 4 + (s & 3);  // 0..63
  const int kh = ct >> 2, cb = ct & 3;
  const int tid = threadIdx.x;
  const int wv = tid >> 6, lane = tid & 63;
  const int wr = wv >> 2, wc = wv & 3;
  const int l15 = lane & 15, l4 = lane >> 4;

  const signed char* Ab = xq + (size_t)mt * 256 * DIM;
  const signed char* Bb = Wq + (size_t)ct * 256 * DIM;

  i32x4 acc[8][4];
  #pragma unroll
  for (int i = 0; i < 8; ++i)
    #pragma unroll
    for (int j = 0; j < 4; ++j) acc[i][j] = (i32x4){0, 0, 0, 0};

  // stage tile t (rows of 128 int8) -> buf t&1; inverse-swizzled source
  // (byte bits 4-6 of the k-offset XOR row bits 1-3); linear LDS dest.
  auto stageA_h = [&](int t, int half) {
    const int buf = t & 1, db = t << 7;
    #pragma unroll
    for (int pp = 0; pp < 2; ++pp) {
      const int p = half * 2 + pp;
      const int r = p * 64 + (tid >> 3);
      const int ksrc = ((tid & 7) * 16) ^ (((r >> 1) & 7) << 4);
      gload_lds16(Ab + (size_t)r * DIM + db + ksrc,
                  (char*)&As[buf][0] + p * 8192 + wv * 1024);
    }
  };
  auto stageB_h = [&](int t, int half) {
    const int buf = t & 1, db = t << 7;
    #pragma unroll
    for (int pp = 0; pp < 2; ++pp) {
      const int p = half * 2 + pp;
      const int r = p * 64 + (tid >> 3);
      const int ksrc = ((tid & 7) * 16) ^ (((r >> 1) & 7) << 4);
      gload_lds16(Bb + (size_t)r * DIM + db + ksrc,
                  (char*)&Bs[buf][0] + p * 8192 + wv * 1024);
    }
  };

  // hoisted swizzled read addresses; swz = row bits1-3 = l15 bits1-3 (per-lane const)
  const int swz = ((l15 >> 1) & 7) << 4;
  const int kb0 = (0 * 64 + l4 * 16) ^ swz;    // khalf 0
  const int kb1 = (1 * 64 + l4 * 16) ^ swz;    // khalf 1
  const int aRow = (wr * 128 + l15) * 128;     // frag f: +f*2048
  const int bRow = (wc * 64 + l15) * 128;      // frag nf: +nf*2048

  i32x4 a[8], b[4], a2[8], b2[4];

  stageA_h(0, 0); stageA_h(0, 1); stageB_h(0, 0); stageB_h(0, 1);
  stageA_h(1, 0); stageA_h(1, 1); stageB_h(1, 0); stageB_h(1, 1);
  __syncthreads();

  for (int u = 0; u < 8; ++u) {
    const int buf = u & 1;
    const char* Abase = (const char*)&As[buf][0];
    const char* Bbase = (const char*)&Bs[buf][0];
    // khalf 0 fragments
    #pragma unroll
    for (int f = 0; f < 8; ++f) a[f] = *(const i32x4*)(Abase + aRow + f * 2048 + kb0);
    #pragma unroll
    for (int nf = 0; nf < 4; ++nf) b[nf] = *(const i32x4*)(Bbase + bRow + nf * 2048 + kb0);
    if (u < 7) { stageA_h(u + 1, 0); stageB_h(u + 1, 0); }
    // khalf 1 fragments (independent of khalf-0 MFMAs -> scheduler may overlap)
    #pragma unroll
    for (int f = 0; f < 8; ++f) a2[f] = *(const i32x4*)(Abase + aRow + f * 2048 + kb1);
    #pragma unroll
    for (int nf = 0; nf < 4; ++nf) b2[nf] = *(const i32x4*)(Bbase + bRow + nf * 2048 + kb1);
    __builtin_amdgcn_s_setprio(1);
    #pragma unroll
    for (int f = 0; f < 8; ++f)
      #pragma unroll
      for (int nf = 0; nf < 4; ++nf)
        acc[f][nf] = __builtin_amdgcn_mfma_i32_16x16x64_i8(a[f], b[nf], acc[f][nf], 0, 0, 0);
    __builtin_amdgcn_s_setprio(0);
    if (u < 7) { stageA_h(u + 1, 1); stageB_h(u + 1, 1); }
    __builtin_amdgcn_s_setprio(1);
    #pragma unroll
    for (int f = 0; f < 8; ++f)
      #pragma unroll
      for (int nf = 0; nf < 4; ++nf)
        acc[f][nf] = __builtin_amdgcn_mfma_i32_16x16x64_i8(a2[f], b2[nf], acc[f][nf], 0, 0, 0);
    __builtin_amdgcn_s_setprio(0);
    __syncthreads();   // drains stage (vmcnt 0) + read-retire fence
  }

  // ---- gated epilogue with dequant ----
  float partial[8][4];
  #pragma unroll
  for (int f = 0; f < 8; ++f)
    #pragma unroll
    for (int r = 0; r < 4; ++r) partial[f][r] = 0.f;

  float vb[2], ub[2], wwv[2], swv[2], swu[2];
  #pragma unroll
  for (int p = 0; p < 2; ++p) {
    const int hl = (cb * 8 + wc * 2 + p) * 16 + l15;
    vb[p]  = Vb[kh * HID + hl];
    ub[p]  = Ub[kh * HID + hl];
    wwv[p] = ww[kh * HID + hl];
    swv[p] = swp[ct * 256 + wc * 64 + (2 * p) * 16 + l15];
    swu[p] = swp[ct * 256 + wc * 64 + (2 * p + 1) * 16 + l15];
  }
  const int rbase = mt * 256 + wr * 128 + l4 * 4;
  #pragma unroll
  for (int f = 0; f < 8; ++f) {
    const float4 sx4 = *(const float4*)&sx[rbase + f * 16];
    const float sxr[4] = {sx4.x, sx4.y, sx4.z, sx4.w};
    #pragma unroll
    for (int p = 0; p < 2; ++p)
      #pragma unroll
      for (int r = 0; r < 4; ++r) {
        const float scv = (float)acc[f][2 * p][r] * (sxr[r] * swv[p]) + vb[p];
        const float scu = (float)acc[f][2 * p + 1][r] * (sxr[r] * swu[p]) + ub[p];
        const float e2 = __expf(2.f * scv);
        const float av = 1.f - 2.f / (e2 + 1.f);          // tanh
        const float au = 1.f / (1.f + __expf(-scu));      // sigmoid
        partial[f][r] += av * au * wwv[p];
      }
  }
  #pragma unroll
  for (int s2 = 1; s2 < 16; s2 <<= 1)
    #pragma unroll
    for (int f = 0; f < 8; ++f)
      #pragma unroll
      for (int r = 0; r < 4; ++r)
        partial[f][r] += __shfl_xor(partial[f][r], s2, 64);

  if (l15 == 0) {
    const int j = cb * 4 + wc;
    float* dst = part + ((size_t)j * NHEAD + kh) * N_PATCH;
    #pragma unroll
    for (int f = 0; f < 8; ++f)
      #pragma unroll
      for (int r = 0; r < 4; ++r)
        dst[rbase + f * 16 + r] = partial[f][r];
  }
}

// ---------------- scores + per-chunk softmax partials (128 blocks) ----------------
__global__ void scores_part_kernel(const float* __restrict__ part,
                                   float* __restrict__ scores,
                                   float* __restrict__ spart) {
  const int k = blockIdx.x >> 3, c = blockIdx.x & 7;
  const int t = threadIdx.x;
  __shared__ float shm[4], shs[4];
  float v[4];
  float mx = -1e30f;
  #pragma unroll
  for (int i = 0; i < 4; ++i) {
    const int n = c * 1024 + i * 256 + t;
    float s = 0.f;
    #pragma unroll
    for (int j = 0; j < 16; ++j) s += part[((size_t)j * NHEAD + k) * N_PATCH + n];
    v[i] = s;
    scores[(size_t)k * N_PATCH + n] = s;
    mx = fmaxf(mx, s);
  }
  #pragma unroll
  for (int sft = 32; sft; sft >>= 1) mx = fmaxf(mx, __shfl_xor(mx, sft, 64));
  const int wv = t >> 6;
  if ((t & 63) == 0) shm[wv] = mx;
  __syncthreads();
  mx = fmaxf(fmaxf(shm[0], shm[1]), fmaxf(shm[2], shm[3]));
  float sum = 0.f;
  #pragma unroll
  for (int i = 0; i < 4; ++i) sum += __expf(v[i] - mx);
  #pragma unroll
  for (int sft = 32; sft; sft >>= 1) sum += __shfl_xor(sum, sft, 64);
  if ((t & 63) == 0) shs[wv] = sum;
  __syncthreads();
  if (t == 0) {
    spart[(k * 8 + c) * 2]     = mx;
    spart[(k * 8 + c) * 2 + 1] = shs[0] + shs[1] + shs[2] + shs[3];
  }
}

// ---------------- fused: stats; w[n]=sum_k softmax; partial col-sums (int8 x + sx) ----
__global__ void weighted_part_kernel(const signed char* __restrict__ xq,
                                     const float* __restrict__ sx,
                                     const float* __restrict__ scores,
                                     const float* __restrict__ spart,
                                     float* __restrict__ wp1,
                                     float* __restrict__ wp2) {
  __shared__ float wsx[128], s2x[128];
  __shared__ float sm[16], srz[16];
  const int d = blockIdx.x * 256 + threadIdx.x;
  const int nc = blockIdx.y;
  if (threadIdx.x < 16) {
    const int k = threadIdx.x;
    float m = -1e30f;
    #pragma unroll
    for (int c = 0; c < 8; ++c) m = fmaxf(m, spart[(k * 8 + c) * 2]);
    float S = 0.f;
    #pragma unroll
    for (int c = 0; c < 8; ++c)
      S += spart[(k * 8 + c) * 2 + 1] * __expf(spart[(k * 8 + c) * 2] - m);
    sm[k] = m; srz[k] = 1.f / S;
  }
  __syncthreads();
  if (threadIdx.x < 128) {
    const int n = nc * 128 + threadIdx.x;
    float s = 0.f;
    #pragma unroll
    for (int k = 0; k < NHEAD; ++k)
      s += __expf(scores[(size_t)k * N_PATCH + n] - sm[k]) * srz[k];
    const float sxn = sx[n];
    wsx[threadIdx.x] = s * sxn;
    s2x[threadIdx.x] = sxn;
  }
  __syncthreads();
  float a1 = 0.f, a2 = 0.f;
  for (int i = 0; i < 128; ++i) {
    const float q = (float)xq[(size_t)(nc * 128 + i) * DIM + d];
    a1 += wsx[i] * q;
    a2 += s2x[i] * q;
  }
  wp1[nc * DIM + d] = a1;
  wp2[nc * DIM + d] = a2;
}

__global__ void reduce_vec_kernel(const float* __restrict__ wp1,
                                  const float* __restrict__ wp2,
                                  float* __restrict__ y1,
                                  float* __restrict__ mvec) {
  int d = blockIdx.x * 256 + threadIdx.x;
  float s1 = 0.f, s2 = 0.f;
  #pragma unroll
  for (int i = 0; i < 64; ++i) {
    s1 += wp1[i * DIM + d];
    s2 += wp2[i * DIM + d];
  }
  y1[d] = s1;
  mvec[d] = s2 * (1.f / (float)N_PATCH);
}

// ---------------- one-dispatch GEMV: in-block split-K (4 kc x 64 j) ----------------
__global__ void gemv_fused_kernel(const float* __restrict__ in,
                                  const float* __restrict__ W,
                                  const float* __restrict__ bias,
                                  const float* __restrict__ extra, float scale,
                                  int do_relu, float* __restrict__ out,
                                  int In, int Out) {
  __shared__ float red[4][64];
  const int jl = threadIdx.x & 63, kc = threadIdx.x >> 6;
  const int j = blockIdx.x * 64 + jl;
  const int chunk = In >> 2;
  const float* Wp = W + (size_t)(kc * chunk) * Out + j;
  const float* ip = in + kc * chunk;
  float acc = 0.f;
  #pragma unroll 4
  for (int d = 0; d < chunk; ++d) acc += ip[d] * Wp[(size_t)d * Out];
  if (kc) red[kc][jl] = acc;
  __syncthreads();
  if (kc == 0) {
    float v = bias[j] + acc + red[1][jl] + red[2][jl] + red[3][jl];
    if (extra) v += extra[j];
    v *= scale;
    if (do_relu) v = fmaxf(v, 0.f);
    out[j] = v;
  }
}

// ---------------- fused: c3 = relu(c2@cW3+cb3); logits; softmax ----------------
__global__ void c3_final_kernel(const float* __restrict__ c2,
                                const float* __restrict__ W3,
                                const float* __restrict__ b3,
                                const float* __restrict__ W4,
                                const float* __restrict__ b4,
                                float* __restrict__ out) {
  __shared__ float c3s[256];
  __shared__ float logits[9];
  const int t = threadIdx.x;
  float acc = b3[t];
  #pragma unroll 4
  for (int d = 0; d < 512; ++d) acc += c2[d] * W3[(size_t)d * 256 + t];
  c3s[t] = fmaxf(acc, 0.f);
  __syncthreads();
  if (t < 9) {
    float l = b4[t];
    for (int d = 0; d < 256; ++d) l += c3s[d] * W4[d * 9 + t];
    logits[t] = l;
  }
  __syncthreads();
  if (t == 0) {
    float mx = logits[0];
    for (int j = 1; j < 9; ++j) mx = fmaxf(mx, logits[j]);
    float e[9], s = 0.f;
    for (int j = 0; j < 9; ++j) { e[j] = expf(logits[j] - mx); s += e[j]; }
    for (int j = 0; j < 9; ++j) out[j] = e[j] / s;
  }
}

extern "C" void kernel_launch(void* const* d_in, const int* in_sizes, int n_in,
                              void* d_out, int out_size, void* d_ws, size_t ws_size,
                              hipStream_t stream) {
  (void)in_sizes; (void)n_in; (void)out_size; (void)ws_size;
  const float* x   = (const float*)d_in[0];
  const float* Vw  = (const float*)d_in[1];
  const float* Vb  = (const float*)d_in[2];
  const float* Uw  = (const float*)d_in[3];
  const float* Ub  = (const float*)d_in[4];
  const float* ww  = (const float*)d_in[5];
  // d_in[6] = wb: constant per head -> softmax invariant -> unused
  const float* pW1 = (const float*)d_in[7];
  const float* pb1 = (const float*)d_in[8];
  const float* pW2 = (const float*)d_in[9];
  const float* pb2 = (const float*)d_in[10];
  const float* cW1 = (const float*)d_in[11];
  const float* cb1 = (const float*)d_in[12];
  const float* cW2 = (const float*)d_in[13];
  const float* cb2 = (const float*)d_in[14];
  const float* cW3 = (const float*)d_in[15];
  const float* cb3 = (const float*)d_in[16];
  const float* cW4 = (const float*)d_in[17];
  const float* cb4 = (const float*)d_in[18];
  float* out = (float*)d_out;

  char* ws = (char*)d_ws;
  size_t o = 0;
  auto alloc = [&](size_t bytes) -> char* {
    char* p = ws + o;
    o += (bytes + 255) & ~(size_t)255;
    return p;
  };
  signed char* xq = (signed char*)alloc((size_t)N_PATCH * DIM);       // 8 MB
  signed char* Wq = (signed char*)alloc((size_t)NHEAD * 1024 * DIM);  // 16 MB
  float* sx    = (float*)alloc(N_PATCH * 4);
  float* swp   = (float*)alloc(NHEAD * 1024 * 4);
  float* rswp  = (float*)alloc(NHEAD * 1024 * 4);
  float* part  = (float*)alloc((size_t)16 * NHEAD * N_PATCH * 4);     // 8 MB
  float* scores= (float*)alloc((size_t)NHEAD * N_PATCH * 4);
  float* spart = (float*)alloc(NHEAD * 8 * 2 * 4);
  float* wp1   = (float*)alloc(64 * DIM * 4);
  float* wp2   = (float*)alloc(64 * DIM * 4);
  float* y1    = (float*)alloc(DIM * 4);
  float* mvec  = (float*)alloc(DIM * 4);
  float* h1    = (float*)alloc(HID * 4);
  float* aggr  = (float*)alloc(DIM * 4);
  float* c1    = (float*)alloc(1024 * 4);
  float* c2    = (float*)alloc(512 * 4);

  prep1_kernel<<<2304, 256, 0, stream>>>(x, xq, sx, Vw, Uw, swp, rswp);
  pack_wq_kernel<<<2048, 256, 0, stream>>>(Vw, Uw, rswp, Wq);
  gemm_scores_kernel<<<2048, 512, 0, stream>>>(xq, Wq, sx, swp, Vb, Ub, ww, part);
  scores_part_kernel<<<128, 256, 0, stream>>>(part, scores, spart);
  weighted_part_kernel<<<dim3(4, 64), 256, 0, stream>>>(xq, sx, scores, spart, wp1, wp2);
  reduce_vec_kernel<<<4, 256, 0, stream>>>(wp1, wp2, y1, mvec);
  gemv_fused_kernel<<<8, 256, 0, stream>>>(mvec, pW1, pb1, nullptr, 1.f, 1, h1, DIM, HID);
  gemv_fused_kernel<<<16, 256, 0, stream>>>(h1, pW2, pb2, y1, 1.f / 17.f, 0, aggr, HID, DIM);
  gemv_fused_kernel<<<16, 256, 0, stream>>>(aggr, cW1, cb1, nullptr, 1.f, 1, c1, 1024, 1024);
  gemv_fused_kernel<<<8, 256, 0, stream>>>(c1, cW2, cb2, nullptr, 1.f, 1, c2, 1024, 512);
  c3_final_kernel<<<1, 256, 0, stream>>>(c2, cW3, cb3, cW4, cb4, out);
}

// Round 16
// 371.432 us; speedup vs baseline: 3.9635x; 1.0343x over previous
//
#include <hip/hip_runtime.h>
#include <stdint.h>

#define N_PATCH 8192
#define DIM     1024
#define HID     512
#define NHEAD   16

using i32x4 = __attribute__((ext_vector_type(4))) int;

__device__ __forceinline__ void gload_lds16(const void* g, void* l) {
  __builtin_amdgcn_global_load_lds(
      reinterpret_cast<const __attribute__((address_space(1))) void*>(
          reinterpret_cast<uintptr_t>(g)),
      reinterpret_cast<__attribute__((address_space(3))) void*>(
          reinterpret_cast<uintptr_t>(l)),
      16, 0, 0);
}

__device__ __forceinline__ int q8(float v, float rs) {
  int q = (int)rintf(v * rs);
  return q > 127 ? 127 : (q < -127 ? -127 : q);
}

// ---------------- prep1: quantize x per-row (bid<2048) + W column amax (bid>=2048, 256 blk) ----
__global__ void prep1_kernel(const float* __restrict__ x,
                             signed char* __restrict__ xq, float* __restrict__ sx,
                             const float* __restrict__ Vw, const float* __restrict__ Uw,
                             float* __restrict__ swp, float* __restrict__ rswp) {
  __shared__ __align__(16) float red4[16][16][4];   // 4 KB
  const int bid = blockIdx.x;
  const int t = threadIdx.x;
  if (bid < 2048) {            // ---- x: one wave per row, 4 rows/block ----
    const int row = bid * 4 + (t >> 6);
    const int lane = t & 63;
    const float* xr = x + (size_t)row * DIM;
    float4 v[4];
    float am = 0.f;
    #pragma unroll
    for (int j = 0; j < 4; ++j) {
      v[j] = *(const float4*)&xr[j * 256 + lane * 4];
      am = fmaxf(am, fmaxf(fmaxf(fabsf(v[j].x), fabsf(v[j].y)),
                           fmaxf(fabsf(v[j].z), fabsf(v[j].w))));
    }
    #pragma unroll
    for (int s = 32; s; s >>= 1) am = fmaxf(am, __shfl_xor(am, s, 64));
    const float rs = (am > 0.f) ? 127.f / am : 0.f;
    #pragma unroll
    for (int j = 0; j < 4; ++j) {
      int b = (q8(v[j].x, rs) & 255) | ((q8(v[j].y, rs) & 255) << 8) |
              ((q8(v[j].z, rs) & 255) << 16) | ((q8(v[j].w, rs) & 255) << 24);
      ((int*)xq)[row * 256 + j * 64 + lane] = b;
    }
    if (lane == 0) sx[row] = am / 127.f;
    return;
  }
  // ---- W column amax: 256 blocks = u(2) x k(16) x hc(8), 64 cols each ----
  const int b2 = bid - 2048;
  const int u = b2 >> 7, k = (b2 >> 3) & 15, hc = b2 & 7;
  const float* W = u ? Uw : Vw;
  const int h4 = t & 15, dseg = t >> 4;   // 16 h-groups x 16 d-segs
  const size_t base = (size_t)k * DIM * HID + hc * 64 + h4 * 4;
  float4 am4 = {0.f, 0.f, 0.f, 0.f};
  for (int i = 0; i < 64; ++i) {
    float4 v = *(const float4*)&W[base + (size_t)(dseg * 64 + i) * HID];
    am4.x = fmaxf(am4.x, fabsf(v.x));
    am4.y = fmaxf(am4.y, fabsf(v.y));
    am4.z = fmaxf(am4.z, fabsf(v.z));
    am4.w = fmaxf(am4.w, fabsf(v.w));
  }
  *(float4*)&red4[dseg][h4][0] = am4;
  __syncthreads();
  if (t < 64) {
    float m = 0.f;
    #pragma unroll
    for (int ds = 0; ds < 16; ++ds) m = fmaxf(m, red4[ds][t >> 2][t & 3]);
    const int h = hc * 64 + t;
    const int c = (h >> 4) * 32 + u * 16 + (h & 15);
    swp[k * 1024 + c]  = m / 127.f;
    rswp[k * 1024 + c] = (m > 0.f) ? 127.f / m : 0.f;
  }
}

// ---------------- pack W -> Wq[col][d] int8 via LDS transpose (2048 blk: k16 x hc8 x dc16) ----
__global__ void pack_wq_kernel(const float* __restrict__ Vw,
                               const float* __restrict__ Uw,
                               const float* __restrict__ rswp,
                               signed char* __restrict__ Wq) {
  __shared__ __align__(16) signed char T[128][80];   // pad 80: <=2-way on i32x4 reads
  const int bid = blockIdx.x;
  const int k = bid >> 7, hc = (bid >> 4) & 7, dc = bid & 15;
  const int t = threadIdx.x;
  const int d0 = dc * 64, h0 = hc * 64;
  const int hh = t & 63;                 // fixed per thread
  const size_t base = (size_t)k * DIM * HID;
  #pragma unroll
  for (int u = 0; u < 2; ++u) {
    const float* W = u ? Uw : Vw;
    const int h = h0 + hh;
    const int cl = ((hh >> 4) << 5) + (u << 4) + (hh & 15);
    const float rs = rswp[k * 1024 + hc * 128 + cl];
    #pragma unroll
    for (int i = 0; i < 16; ++i) {
      const int dd = i * 4 + (t >> 6);
      T[cl][dd] = (signed char)q8(W[base + (size_t)(d0 + dd) * HID + h], rs);
    }
  }
  __syncthreads();
  #pragma unroll
  for (int j = 0; j < 2; ++j) {
    const int idx = j * 256 + t;
    const int cl = idx >> 2, dq = idx & 3;
    i32x4 val = *(const i32x4*)&T[cl][dq * 16];
    const size_t col = (size_t)k * 1024 + hc * 128 + cl;
    *(i32x4*)&Wq[col * DIM + d0 + dq * 16] = val;
  }
}

// ---------------- main GEMM (int8) + gated epilogue -> score partials ----------------
// 256x256 tile, BK=128 bytes (8 K-tiles), 8 waves (2M x 4N), mfma_i32_16x16x64_i8,
// 3-bit XOR swizzle on 128B rows, one barrier/K-tile, L2-aware block map,
// cross-wave LDS reduce in epilogue -> ONE part slot per block (4 slots total).
__global__ __launch_bounds__(512, 1) void gemm_scores_kernel(
    const signed char* __restrict__ xq, const signed char* __restrict__ Wq,
    const float* __restrict__ sx, const float* __restrict__ swp,
    const float* __restrict__ Vb, const float* __restrict__ Ub,
    const float* __restrict__ ww, float* __restrict__ part) {
  __shared__ __align__(16) signed char As[2][32768];   // 2 x 32 KB
  __shared__ __align__(16) signed char Bs[2][32768];
  const int bid = blockIdx.x;
  const int x8 = bid & 7;
  const int s  = (bid >> 3) & 31;
  const int w  = bid >> 8;
  const int mt = (x8 & 1) * 16 + (w & 1) * 8 + (s >> 2);   // 0..31
  const int ct = (x8 >> 1) * 16 + (w >> 1) * 4 + (s & 3);  // 0..63
  const int kh = ct >> 2, cb = ct & 3;
  const int tid = threadIdx.x;
  const int wv = tid >> 6, lane = tid & 63;
  const int wr = wv >> 2, wc = wv & 3;
  const int l15 = lane & 15, l4 = lane >> 4;

  const signed char* Ab = xq + (size_t)mt * 256 * DIM;
  const signed char* Bb = Wq + (size_t)ct * 256 * DIM;

  i32x4 acc[8][4];
  #pragma unroll
  for (int i = 0; i < 8; ++i)
    #pragma unroll
    for (int j = 0; j < 4; ++j) acc[i][j] = (i32x4){0, 0, 0, 0};

  auto stageA_h = [&](int t, int half) {
    const int buf = t & 1, db = t << 7;
    #pragma unroll
    for (int pp = 0; pp < 2; ++pp) {
      const int p = half * 2 + pp;
      const int r = p * 64 + (tid >> 3);
      const int ksrc = ((tid & 7) * 16) ^ (((r >> 1) & 7) << 4);
      gload_lds16(Ab + (size_t)r * DIM + db + ksrc,
                  (char*)&As[buf][0] + p * 8192 + wv * 1024);
    }
  };
  auto stageB_h = [&](int t, int half) {
    const int buf = t & 1, db = t << 7;
    #pragma unroll
    for (int pp = 0; pp < 2; ++pp) {
      const int p = half * 2 + pp;
      const int r = p * 64 + (tid >> 3);
      const int ksrc = ((tid & 7) * 16) ^ (((r >> 1) & 7) << 4);
      gload_lds16(Bb + (size_t)r * DIM + db + ksrc,
                  (char*)&Bs[buf][0] + p * 8192 + wv * 1024);
    }
  };

  const int swz = ((l15 >> 1) & 7) << 4;
  const int kb0 = (0 * 64 + l4 * 16) ^ swz;    // khalf 0
  const int kb1 = (1 * 64 + l4 * 16) ^ swz;    // khalf 1
  const int aRow = (wr * 128 + l15) * 128;     // frag f: +f*2048
  const int bRow = (wc * 64 + l15) * 128;      // frag nf: +nf*2048

  i32x4 a[8], b[4], a2[8], b2[4];

  stageA_h(0, 0); stageA_h(0, 1); stageB_h(0, 0); stageB_h(0, 1);
  stageA_h(1, 0); stageA_h(1, 1); stageB_h(1, 0); stageB_h(1, 1);
  __syncthreads();

  for (int u = 0; u < 8; ++u) {
    const int buf = u & 1;
    const char* Abase = (const char*)&As[buf][0];
    const char* Bbase = (const char*)&Bs[buf][0];
    #pragma unroll
    for (int f = 0; f < 8; ++f) a[f] = *(const i32x4*)(Abase + aRow + f * 2048 + kb0);
    #pragma unroll
    for (int nf = 0; nf < 4; ++nf) b[nf] = *(const i32x4*)(Bbase + bRow + nf * 2048 + kb0);
    if (u < 7) { stageA_h(u + 1, 0); stageB_h(u + 1, 0); }
    #pragma unroll
    for (int f = 0; f < 8; ++f) a2[f] = *(const i32x4*)(Abase + aRow + f * 2048 + kb1);
    #pragma unroll
    for (int nf = 0; nf < 4; ++nf) b2[nf] = *(const i32x4*)(Bbase + bRow + nf * 2048 + kb1);
    __builtin_amdgcn_s_setprio(1);
    #pragma unroll
    for (int f = 0; f < 8; ++f)
      #pragma unroll
      for (int nf = 0; nf < 4; ++nf)
        acc[f][nf] = __builtin_amdgcn_mfma_i32_16x16x64_i8(a[f], b[nf], acc[f][nf], 0, 0, 0);
    __builtin_amdgcn_s_setprio(0);
    if (u < 7) { stageA_h(u + 1, 1); stageB_h(u + 1, 1); }
    __builtin_amdgcn_s_setprio(1);
    #pragma unroll
    for (int f = 0; f < 8; ++f)
      #pragma unroll
      for (int nf = 0; nf < 4; ++nf)
        acc[f][nf] = __builtin_amdgcn_mfma_i32_16x16x64_i8(a2[f], b2[nf], acc[f][nf], 0, 0, 0);
    __builtin_amdgcn_s_setprio(0);
    __syncthreads();
  }

  // ---- gated epilogue with dequant ----
  float partial[8][4];
  #pragma unroll
  for (int f = 0; f < 8; ++f)
    #pragma unroll
    for (int r = 0; r < 4; ++r) partial[f][r] = 0.f;

  float vb[2], ub[2], wwv[2], swv[2], swu[2];
  #pragma unroll
  for (int p = 0; p < 2; ++p) {
    const int hl = (cb * 8 + wc * 2 + p) * 16 + l15;
    vb[p]  = Vb[kh * HID + hl];
    ub[p]  = Ub[kh * HID + hl];
    wwv[p] = ww[kh * HID + hl];
    swv[p] = swp[ct * 256 + wc * 64 + (2 * p) * 16 + l15];
    swu[p] = swp[ct * 256 + wc * 64 + (2 * p + 1) * 16 + l15];
  }
  const int rbase = mt * 256 + wr * 128 + l4 * 4;
  #pragma unroll
  for (int f = 0; f < 8; ++f) {
    const float4 sx4 = *(const float4*)&sx[rbase + f * 16];
    const float sxr[4] = {sx4.x, sx4.y, sx4.z, sx4.w};
    #pragma unroll
    for (int p = 0; p < 2; ++p)
      #pragma unroll
      for (int r = 0; r < 4; ++r) {
        const float scv = (float)acc[f][2 * p][r] * (sxr[r] * swv[p]) + vb[p];
        const float scu = (float)acc[f][2 * p + 1][r] * (sxr[r] * swu[p]) + ub[p];
        const float e2 = __expf(2.f * scv);
        const float av = 1.f - 2.f / (e2 + 1.f);          // tanh
        const float au = 1.f / (1.f + __expf(-scu));      // sigmoid
        partial[f][r] += av * au * wwv[p];
      }
  }
  #pragma unroll
  for (int s2 = 1; s2 < 16; s2 <<= 1)
    #pragma unroll
    for (int f = 0; f < 8; ++f)
      #pragma unroll
      for (int r = 0; r < 4; ++r)
        partial[f][r] += __shfl_xor(partial[f][r], s2, 64);

  // ---- cross-wave reduce over wc (4 waves share cb): one part slot per block ----
  float* red = (float*)&As[0][0];   // 2*4*128 floats = 4 KB (As dead after loop)
  if (l15 == 0) {
    #pragma unroll
    for (int f = 0; f < 8; ++f)
      #pragma unroll
      for (int r = 0; r < 4; ++r)
        red[(wr * 4 + wc) * 128 + f * 16 + l4 * 4 + r] = partial[f][r];
  }
  __syncthreads();
  if (tid < 256) {
    const int row = tid;                 // 0..255 within the 256-row tile
    const int wr2 = row >> 7, lr = row & 127;
    const float* rp = red + wr2 * 4 * 128;
    const float v = rp[lr] + rp[128 + lr] + rp[256 + lr] + rp[384 + lr];
    part[((size_t)cb * NHEAD + kh) * N_PATCH + mt * 256 + row] = v;
  }
}

// ---------------- scores + per-chunk softmax partials (128 blocks) ----------------
__global__ void scores_part_kernel(const float* __restrict__ part,
                                   float* __restrict__ scores,
                                   float* __restrict__ spart) {
  const int k = blockIdx.x >> 3, c = blockIdx.x & 7;
  const int t = threadIdx.x;
  __shared__ float shm[4], shs[4];
  float v[4];
  float mx = -1e30f;
  #pragma unroll
  for (int i = 0; i < 4; ++i) {
    const int n = c * 1024 + i * 256 + t;
    float s = 0.f;
    #pragma unroll
    for (int j = 0; j < 4; ++j) s += part[((size_t)j * NHEAD + k) * N_PATCH + n];
    v[i] = s;
    scores[(size_t)k * N_PATCH + n] = s;
    mx = fmaxf(mx, s);
  }
  #pragma unroll
  for (int sft = 32; sft; sft >>= 1) mx = fmaxf(mx, __shfl_xor(mx, sft, 64));
  const int wv = t >> 6;
  if ((t & 63) == 0) shm[wv] = mx;
  __syncthreads();
  mx = fmaxf(fmaxf(shm[0], shm[1]), fmaxf(shm[2], shm[3]));
  float sum = 0.f;
  #pragma unroll
  for (int i = 0; i < 4; ++i) sum += __expf(v[i] - mx);
  #pragma unroll
  for (int sft = 32; sft; sft >>= 1) sum += __shfl_xor(sum, sft, 64);
  if ((t & 63) == 0) shs[wv] = sum;
  __syncthreads();
  if (t == 0) {
    spart[(k * 8 + c) * 2]     = mx;
    spart[(k * 8 + c) * 2 + 1] = shs[0] + shs[1] + shs[2] + shs[3];
  }
}

// ---------------- fused: stats; w[n]=sum_k softmax; partial col-sums (int8 x + sx) ----
__global__ void weighted_part_kernel(const signed char* __restrict__ xq,
                                     const float* __restrict__ sx,
                                     const float* __restrict__ scores,
                                     const float* __restrict__ spart,
                                     float* __restrict__ wp1,
                                     float* __restrict__ wp2) {
  __shared__ float wsx[128], s2x[128];
  __shared__ float sm[16], srz[16];
  const int d = blockIdx.x * 256 + threadIdx.x;
  const int nc = blockIdx.y;
  if (threadIdx.x < 16) {
    const int k = threadIdx.x;
    float m = -1e30f;
    #pragma unroll
    for (int c = 0; c < 8; ++c) m = fmaxf(m, spart[(k * 8 + c) * 2]);
    float S = 0.f;
    #pragma unroll
    for (int c = 0; c < 8; ++c)
      S += spart[(k * 8 + c) * 2 + 1] * __expf(spart[(k * 8 + c) * 2] - m);
    sm[k] = m; srz[k] = 1.f / S;
  }
  __syncthreads();
  if (threadIdx.x < 128) {
    const int n = nc * 128 + threadIdx.x;
    float s = 0.f;
    #pragma unroll
    for (int k = 0; k < NHEAD; ++k)
      s += __expf(scores[(size_t)k * N_PATCH + n] - sm[k]) * srz[k];
    const float sxn = sx[n];
    wsx[threadIdx.x] = s * sxn;
    s2x[threadIdx.x] = sxn;
  }
  __syncthreads();
  float a1 = 0.f, a2 = 0.f;
  for (int i = 0; i < 128; ++i) {
    const float q = (float)xq[(size_t)(nc * 128 + i) * DIM + d];
    a1 += wsx[i] * q;
    a2 += s2x[i] * q;
  }
  wp1[nc * DIM + d] = a1;
  wp2[nc * DIM + d] = a2;
}

__global__ void reduce_vec_kernel(const float* __restrict__ wp1,
                                  const float* __restrict__ wp2,
                                  float* __restrict__ y1,
                                  float* __restrict__ mvec) {
  int d = blockIdx.x * 256 + threadIdx.x;
  float s1 = 0.f, s2 = 0.f;
  #pragma unroll
  for (int i = 0; i < 64; ++i) {
    s1 += wp1[i * DIM + d];
    s2 += wp2[i * DIM + d];
  }
  y1[d] = s1;
  mvec[d] = s2 * (1.f / (float)N_PATCH);
}

// ---------------- one-dispatch GEMV: in-block split-K (4 kc x 64 j) ----------------
__global__ void gemv_fused_kernel(const float* __restrict__ in,
                                  const float* __restrict__ W,
                                  const float* __restrict__ bias,
                                  const float* __restrict__ extra, float scale,
                                  int do_relu, float* __restrict__ out,
                                  int In, int Out) {
  __shared__ float red[4][64];
  const int jl = threadIdx.x & 63, kc = threadIdx.x >> 6;
  const int j = blockIdx.x * 64 + jl;
  const int chunk = In >> 2;
  const float* Wp = W + (size_t)(kc * chunk) * Out + j;
  const float* ip = in + kc * chunk;
  float acc = 0.f;
  #pragma unroll 4
  for (int d = 0; d < chunk; ++d) acc += ip[d] * Wp[(size_t)d * Out];
  if (kc) red[kc][jl] = acc;
  __syncthreads();
  if (kc == 0) {
    float v = bias[j] + acc + red[1][jl] + red[2][jl] + red[3][jl];
    if (extra) v += extra[j];
    v *= scale;
    if (do_relu) v = fmaxf(v, 0.f);
    out[j] = v;
  }
}

// ---------------- fused: c3 = relu(c2@cW3+cb3); logits; softmax ----------------
__global__ void c3_final_kernel(const float* __restrict__ c2,
                                const float* __restrict__ W3,
                                const float* __restrict__ b3,
                                const float* __restrict__ W4,
                                const float* __restrict__ b4,
                                float* __restrict__ out) {
  __shared__ float c3s[256];
  __shared__ float logits[9];
  const int t = threadIdx.x;
  float acc = b3[t];
  #pragma unroll 4
  for (int d = 0; d < 512; ++d) acc += c2[d] * W3[(size_t)d * 256 + t];
  c3s[t] = fmaxf(acc, 0.f);
  __syncthreads();
  if (t < 9) {
    float l = b4[t];
    for (int d = 0; d < 256; ++d) l += c3s[d] * W4[d * 9 + t];
    logits[t] = l;
  }
  __syncthreads();
  if (t == 0) {
    float mx = logits[0];
    for (int j = 1; j < 9; ++j) mx = fmaxf(mx, logits[j]);
    float e[9], s = 0.f;
    for (int j = 0; j < 9; ++j) { e[j] = expf(logits[j] - mx); s += e[j]; }
    for (int j = 0; j < 9; ++j) out[j] = e[j] / s;
  }
}

extern "C" void kernel_launch(void* const* d_in, const int* in_sizes, int n_in,
                              void* d_out, int out_size, void* d_ws, size_t ws_size,
                              hipStream_t stream) {
  (void)in_sizes; (void)n_in; (void)out_size; (void)ws_size;
  const float* x   = (const float*)d_in[0];
  const float* Vw  = (const float*)d_in[1];
  const float* Vb  = (const float*)d_in[2];
  const float* Uw  = (const float*)d_in[3];
  const float* Ub  = (const float*)d_in[4];
  const float* ww  = (const float*)d_in[5];
  // d_in[6] = wb: constant per head -> softmax invariant -> unused
  const float* pW1 = (const float*)d_in[7];
  const float* pb1 = (const float*)d_in[8];
  const float* pW2 = (const float*)d_in[9];
  const float* pb2 = (const float*)d_in[10];
  const float* cW1 = (const float*)d_in[11];
  const float* cb1 = (const float*)d_in[12];
  const float* cW2 = (const float*)d_in[13];
  const float* cb2 = (const float*)d_in[14];
  const float* cW3 = (const float*)d_in[15];
  const float* cb3 = (const float*)d_in[16];
  const float* cW4 = (const float*)d_in[17];
  const float* cb4 = (const float*)d_in[18];
  float* out = (float*)d_out;

  char* ws = (char*)d_ws;
  size_t o = 0;
  auto alloc = [&](size_t bytes) -> char* {
    char* p = ws + o;
    o += (bytes + 255) & ~(size_t)255;
    return p;
  };
  signed char* xq = (signed char*)alloc((size_t)N_PATCH * DIM);       // 8 MB
  signed char* Wq = (signed char*)alloc((size_t)NHEAD * 1024 * DIM);  // 16 MB
  float* sx    = (float*)alloc(N_PATCH * 4);
  float* swp   = (float*)alloc(NHEAD * 1024 * 4);
  float* rswp  = (float*)alloc(NHEAD * 1024 * 4);
  float* part  = (float*)alloc((size_t)4 * NHEAD * N_PATCH * 4);      // 2 MB
  float* scores= (float*)alloc((size_t)NHEAD * N_PATCH * 4);
  float* spart = (float*)alloc(NHEAD * 8 * 2 * 4);
  float* wp1   = (float*)alloc(64 * DIM * 4);
  float* wp2   = (float*)alloc(64 * DIM * 4);
  float* y1    = (float*)alloc(DIM * 4);
  float* mvec  = (float*)alloc(DIM * 4);
  float* h1    = (float*)alloc(HID * 4);
  float* aggr  = (float*)alloc(DIM * 4);
  float* c1    = (float*)alloc(1024 * 4);
  float* c2    = (float*)alloc(512 * 4);

  prep1_kernel<<<2304, 256, 0, stream>>>(x, xq, sx, Vw, Uw, swp, rswp);
  pack_wq_kernel<<<2048, 256, 0, stream>>>(Vw, Uw, rswp, Wq);
  gemm_scores_kernel<<<2048, 512, 0, stream>>>(xq, Wq, sx, swp, Vb, Ub, ww, part);
  scores_part_kernel<<<128, 256, 0, stream>>>(part, scores, spart);
  weighted_part_kernel<<<dim3(4, 64), 256, 0, stream>>>(xq, sx, scores, spart, wp1, wp2);
  reduce_vec_kernel<<<4, 256, 0, stream>>>(wp1, wp2, y1, mvec);
  gemv_fused_kernel<<<8, 256, 0, stream>>>(mvec, pW1, pb1, nullptr, 1.f, 1, h1, DIM, HID);
  gemv_fused_kernel<<<16, 256, 0, stream>>>(h1, pW2, pb2, y1, 1.f / 17.f, 0, aggr, HID, DIM);
  gemv_fused_kernel<<<16, 256, 0, stream>>>(aggr, cW1, cb1, nullptr, 1.f, 1, c1, 1024, 1024);
  gemv_fused_kernel<<<8, 256, 0, stream>>>(c1, cW2, cb2, nullptr, 1.f, 1, c2, 1024, 512);
  c3_final_kernel<<<1, 256, 0, stream>>>(c2, cW3, cb3, cW4, cb4, out);
}

// Round 17
// 364.550 us; speedup vs baseline: 4.0383x; 1.0189x over previous
//
#include <hip/hip_runtime.h>
#include <stdint.h>

#define N_PATCH 8192
#define DIM     1024
#define HID     512
#define NHEAD   16

using i32x4 = __attribute__((ext_vector_type(4))) int;

__device__ __forceinline__ void gload_lds16(const void* g, void* l) {
  __builtin_amdgcn_global_load_lds(
      reinterpret_cast<const __attribute__((address_space(1))) void*>(
          reinterpret_cast<uintptr_t>(g)),
      reinterpret_cast<__attribute__((address_space(3))) void*>(
          reinterpret_cast<uintptr_t>(l)),
      16, 0, 0);
}

__device__ __forceinline__ int q8(float v, float rs) {
  int q = (int)rintf(v * rs);
  return q > 127 ? 127 : (q < -127 ? -127 : q);
}

// ---------------- prep1: quantize x per-row (2048 blocks) ----------------
__global__ void prep1_kernel(const float* __restrict__ x,
                             signed char* __restrict__ xq, float* __restrict__ sx) {
  const int bid = blockIdx.x;
  const int t = threadIdx.x;
  const int row = bid * 4 + (t >> 6);
  const int lane = t & 63;
  const float* xr = x + (size_t)row * DIM;
  float4 v[4];
  float am = 0.f;
  #pragma unroll
  for (int j = 0; j < 4; ++j) {
    v[j] = *(const float4*)&xr[j * 256 + lane * 4];
    am = fmaxf(am, fmaxf(fmaxf(fabsf(v[j].x), fabsf(v[j].y)),
                         fmaxf(fabsf(v[j].z), fabsf(v[j].w))));
  }
  #pragma unroll
  for (int s = 32; s; s >>= 1) am = fmaxf(am, __shfl_xor(am, s, 64));
  const float rs = (am > 0.f) ? 127.f / am : 0.f;
  #pragma unroll
  for (int j = 0; j < 4; ++j) {
    int b = (q8(v[j].x, rs) & 255) | ((q8(v[j].y, rs) & 255) << 8) |
            ((q8(v[j].z, rs) & 255) << 16) | ((q8(v[j].w, rs) & 255) << 24);
    ((int*)xq)[row * 256 + j * 64 + lane] = b;
  }
  if (lane == 0) sx[row] = am / 127.f;
}

// ---------------- fused W amax + quantize + pack (256 blocks = u2 x k16 x hc8) ----
// Each block: 64 full-depth columns. Phase 1: amax (HBM read, 256 KB).
// Phase 2: re-read (L2-hot) -> quantize -> LDS transpose -> packed i32x4 writes.
__global__ void pack_wq_kernel(const float* __restrict__ Vw,
                               const float* __restrict__ Uw,
                               float* __restrict__ swp,
                               signed char* __restrict__ Wq) {
  __shared__ __align__(16) float redm[16][64];       // 4 KB
  __shared__ float rsL[64];
  __shared__ __align__(16) signed char T[64][288];   // 18 KB (stride 288 = 16-aligned)
  const int bid = blockIdx.x;
  const int u = bid >> 7, k = (bid >> 3) & 15, hc = bid & 7;
  const float* W = u ? Uw : Vw;
  const int t = threadIdx.x;
  const size_t base = (size_t)k * DIM * HID + hc * 64;

  // ---- phase 1: per-column amax ----
  {
    const int h4 = t & 15, dseg = t >> 4;   // 16 h-groups x 16 d-segs of 64
    float4 am4 = {0.f, 0.f, 0.f, 0.f};
    for (int i = 0; i < 64; ++i) {
      float4 v = *(const float4*)&W[base + (size_t)(dseg * 64 + i) * HID + h4 * 4];
      am4.x = fmaxf(am4.x, fabsf(v.x));
      am4.y = fmaxf(am4.y, fabsf(v.y));
      am4.z = fmaxf(am4.z, fabsf(v.z));
      am4.w = fmaxf(am4.w, fabsf(v.w));
    }
    *(float4*)&redm[dseg][h4 * 4] = am4;
  }
  __syncthreads();
  if (t < 64) {
    float m = 0.f;
    #pragma unroll
    for (int ds = 0; ds < 16; ++ds) m = fmaxf(m, redm[ds][t]);
    const int c = k * 1024 + hc * 128 + ((t >> 4) << 5) + (u << 4) + (t & 15);
    swp[c] = m / 127.f;
    rsL[t] = (m > 0.f) ? 127.f / m : 0.f;
  }
  __syncthreads();

  // ---- phase 2: quantize + pack, 4 chunks of 256 d ----
  const int ch = t & 15, rg = t >> 4;       // ch: 4 cols; rg: 16 d-rows of 16
  const float rs0 = rsL[ch * 4 + 0], rs1 = rsL[ch * 4 + 1];
  const float rs2 = rsL[ch * 4 + 2], rs3 = rsL[ch * 4 + 3];
  for (int c256 = 0; c256 < 4; ++c256) {
    #pragma unroll
    for (int i = 0; i < 16; ++i) {
      const int dl = rg * 16 + i;
      float4 v = *(const float4*)&W[base + (size_t)(c256 * 256 + dl) * HID + ch * 4];
      T[ch * 4 + 0][dl] = (signed char)q8(v.x, rs0);
      T[ch * 4 + 1][dl] = (signed char)q8(v.y, rs1);
      T[ch * 4 + 2][dl] = (signed char)q8(v.z, rs2);
      T[ch * 4 + 3][dl] = (signed char)q8(v.w, rs3);
    }
    __syncthreads();
    #pragma unroll
    for (int j = 0; j < 4; ++j) {
      const int idx = j * 256 + t;
      const int hh = idx >> 4, dq = idx & 15;
      i32x4 val = *(const i32x4*)&T[hh][dq * 16];
      const size_t c = (size_t)k * 1024 + hc * 128 + ((hh >> 4) << 5) + (u << 4) + (hh & 15);
      *(i32x4*)&Wq[c * DIM + c256 * 256 + dq * 16] = val;
    }
    __syncthreads();
  }
}

// ---------------- main GEMM (int8) + gated epilogue -> score partials ----------------
// 256x256 tile, BK=128 bytes (8 K-tiles), 8 waves (2M x 4N), mfma_i32_16x16x64_i8,
// 3-bit XOR swizzle on 128B rows, one barrier/K-tile, L2-aware block map,
// cross-wave LDS reduce in epilogue -> ONE part slot per block (4 slots total).
__global__ __launch_bounds__(512, 1) void gemm_scores_kernel(
    const signed char* __restrict__ xq, const signed char* __restrict__ Wq,
    const float* __restrict__ sx, const float* __restrict__ swp,
    const float* __restrict__ Vb, const float* __restrict__ Ub,
    const float* __restrict__ ww, float* __restrict__ part) {
  __shared__ __align__(16) signed char As[2][32768];   // 2 x 32 KB
  __shared__ __align__(16) signed char Bs[2][32768];
  const int bid = blockIdx.x;
  const int x8 = bid & 7;
  const int s  = (bid >> 3) & 31;
  const int w  = bid >> 8;
  const int mt = (x8 & 1) * 16 + (w & 1) * 8 + (s >> 2);   // 0..31
  const int ct = (x8 >> 1) * 16 + (w >> 1) * 4 + (s & 3);  // 0..63
  const int kh = ct >> 2, cb = ct & 3;
  const int tid = threadIdx.x;
  const int wv = tid >> 6, lane = tid & 63;
  const int wr = wv >> 2, wc = wv & 3;
  const int l15 = lane & 15, l4 = lane >> 4;

  const signed char* Ab = xq + (size_t)mt * 256 * DIM;
  const signed char* Bb = Wq + (size_t)ct * 256 * DIM;

  i32x4 acc[8][4];
  #pragma unroll
  for (int i = 0; i < 8; ++i)
    #pragma unroll
    for (int j = 0; j < 4; ++j) acc[i][j] = (i32x4){0, 0, 0, 0};

  auto stageA_h = [&](int t, int half) {
    const int buf = t & 1, db = t << 7;
    #pragma unroll
    for (int pp = 0; pp < 2; ++pp) {
      const int p = half * 2 + pp;
      const int r = p * 64 + (tid >> 3);
      const int ksrc = ((tid & 7) * 16) ^ (((r >> 1) & 7) << 4);
      gload_lds16(Ab + (size_t)r * DIM + db + ksrc,
                  (char*)&As[buf][0] + p * 8192 + wv * 1024);
    }
  };
  auto stageB_h = [&](int t, int half) {
    const int buf = t & 1, db = t << 7;
    #pragma unroll
    for (int pp = 0; pp < 2; ++pp) {
      const int p = half * 2 + pp;
      const int r = p * 64 + (tid >> 3);
      const int ksrc = ((tid & 7) * 16) ^ (((r >> 1) & 7) << 4);
      gload_lds16(Bb + (size_t)r * DIM + db + ksrc,
                  (char*)&Bs[buf][0] + p * 8192 + wv * 1024);
    }
  };

  const int swz = ((l15 >> 1) & 7) << 4;
  const int kb0 = (0 * 64 + l4 * 16) ^ swz;    // khalf 0
  const int kb1 = (1 * 64 + l4 * 16) ^ swz;    // khalf 1
  const int aRow = (wr * 128 + l15) * 128;     // frag f: +f*2048
  const int bRow = (wc * 64 + l15) * 128;      // frag nf: +nf*2048

  i32x4 a[8], b[4], a2[8], b2[4];

  stageA_h(0, 0); stageA_h(0, 1); stageB_h(0, 0); stageB_h(0, 1);
  stageA_h(1, 0); stageA_h(1, 1); stageB_h(1, 0); stageB_h(1, 1);
  __syncthreads();

  for (int u = 0; u < 8; ++u) {
    const int buf = u & 1;
    const char* Abase = (const char*)&As[buf][0];
    const char* Bbase = (const char*)&Bs[buf][0];
    #pragma unroll
    for (int f = 0; f < 8; ++f) a[f] = *(const i32x4*)(Abase + aRow + f * 2048 + kb0);
    #pragma unroll
    for (int nf = 0; nf < 4; ++nf) b[nf] = *(const i32x4*)(Bbase + bRow + nf * 2048 + kb0);
    if (u < 7) { stageA_h(u + 1, 0); stageB_h(u + 1, 0); }
    #pragma unroll
    for (int f = 0; f < 8; ++f) a2[f] = *(const i32x4*)(Abase + aRow + f * 2048 + kb1);
    #pragma unroll
    for (int nf = 0; nf < 4; ++nf) b2[nf] = *(const i32x4*)(Bbase + bRow + nf * 2048 + kb1);
    __builtin_amdgcn_s_setprio(1);
    #pragma unroll
    for (int f = 0; f < 8; ++f)
      #pragma unroll
      for (int nf = 0; nf < 4; ++nf)
        acc[f][nf] = __builtin_amdgcn_mfma_i32_16x16x64_i8(a[f], b[nf], acc[f][nf], 0, 0, 0);
    __builtin_amdgcn_s_setprio(0);
    if (u < 7) { stageA_h(u + 1, 1); stageB_h(u + 1, 1); }
    __builtin_amdgcn_s_setprio(1);
    #pragma unroll
    for (int f = 0; f < 8; ++f)
      #pragma unroll
      for (int nf = 0; nf < 4; ++nf)
        acc[f][nf] = __builtin_amdgcn_mfma_i32_16x16x64_i8(a2[f], b2[nf], acc[f][nf], 0, 0, 0);
    __builtin_amdgcn_s_setprio(0);
    __syncthreads();
  }

  // ---- gated epilogue with dequant ----
  float partial[8][4];
  #pragma unroll
  for (int f = 0; f < 8; ++f)
    #pragma unroll
    for (int r = 0; r < 4; ++r) partial[f][r] = 0.f;

  float vb[2], ub[2], wwv[2], swv[2], swu[2];
  #pragma unroll
  for (int p = 0; p < 2; ++p) {
    const int hl = (cb * 8 + wc * 2 + p) * 16 + l15;
    vb[p]  = Vb[kh * HID + hl];
    ub[p]  = Ub[kh * HID + hl];
    wwv[p] = ww[kh * HID + hl];
    swv[p] = swp[ct * 256 + wc * 64 + (2 * p) * 16 + l15];
    swu[p] = swp[ct * 256 + wc * 64 + (2 * p + 1) * 16 + l15];
  }
  const int rbase = mt * 256 + wr * 128 + l4 * 4;
  #pragma unroll
  for (int f = 0; f < 8; ++f) {
    const float4 sx4 = *(const float4*)&sx[rbase + f * 16];
    const float sxr[4] = {sx4.x, sx4.y, sx4.z, sx4.w};
    #pragma unroll
    for (int p = 0; p < 2; ++p)
      #pragma unroll
      for (int r = 0; r < 4; ++r) {
        const float scv = (float)acc[f][2 * p][r] * (sxr[r] * swv[p]) + vb[p];
        const float scu = (float)acc[f][2 * p + 1][r] * (sxr[r] * swu[p]) + ub[p];
        const float e2 = __expf(2.f * scv);
        const float av = 1.f - 2.f / (e2 + 1.f);          // tanh
        const float au = 1.f / (1.f + __expf(-scu));      // sigmoid
        partial[f][r] += av * au * wwv[p];
      }
  }
  #pragma unroll
  for (int s2 = 1; s2 < 16; s2 <<= 1)
    #pragma unroll
    for (int f = 0; f < 8; ++f)
      #pragma unroll
      for (int r = 0; r < 4; ++r)
        partial[f][r] += __shfl_xor(partial[f][r], s2, 64);

  // ---- cross-wave reduce over wc (4 waves share cb): one part slot per block ----
  float* red = (float*)&As[0][0];   // 4 KB (As dead after loop)
  if (l15 == 0) {
    #pragma unroll
    for (int f = 0; f < 8; ++f)
      #pragma unroll
      for (int r = 0; r < 4; ++r)
        red[(wr * 4 + wc) * 128 + f * 16 + l4 * 4 + r] = partial[f][r];
  }
  __syncthreads();
  if (tid < 256) {
    const int row = tid;
    const int wr2 = row >> 7, lr = row & 127;
    const float* rp = red + wr2 * 4 * 128;
    const float v = rp[lr] + rp[128 + lr] + rp[256 + lr] + rp[384 + lr];
    part[((size_t)cb * NHEAD + kh) * N_PATCH + mt * 256 + row] = v;
  }
}

// ---------------- scores + per-chunk softmax partials (128 blocks) ----------------
__global__ void scores_part_kernel(const float* __restrict__ part,
                                   float* __restrict__ scores,
                                   float* __restrict__ spart) {
  const int k = blockIdx.x >> 3, c = blockIdx.x & 7;
  const int t = threadIdx.x;
  __shared__ float shm[4], shs[4];
  float v[4];
  float mx = -1e30f;
  #pragma unroll
  for (int i = 0; i < 4; ++i) {
    const int n = c * 1024 + i * 256 + t;
    float s = 0.f;
    #pragma unroll
    for (int j = 0; j < 4; ++j) s += part[((size_t)j * NHEAD + k) * N_PATCH + n];
    v[i] = s;
    scores[(size_t)k * N_PATCH + n] = s;
    mx = fmaxf(mx, s);
  }
  #pragma unroll
  for (int sft = 32; sft; sft >>= 1) mx = fmaxf(mx, __shfl_xor(mx, sft, 64));
  const int wv = t >> 6;
  if ((t & 63) == 0) shm[wv] = mx;
  __syncthreads();
  mx = fmaxf(fmaxf(shm[0], shm[1]), fmaxf(shm[2], shm[3]));
  float sum = 0.f;
  #pragma unroll
  for (int i = 0; i < 4; ++i) sum += __expf(v[i] - mx);
  #pragma unroll
  for (int sft = 32; sft; sft >>= 1) sum += __shfl_xor(sum, sft, 64);
  if ((t & 63) == 0) shs[wv] = sum;
  __syncthreads();
  if (t == 0) {
    spart[(k * 8 + c) * 2]     = mx;
    spart[(k * 8 + c) * 2 + 1] = shs[0] + shs[1] + shs[2] + shs[3];
  }
}

// ---------------- fused: stats; w[n]=sum_k softmax; partial col-sums (int8 x + sx) ----
__global__ void weighted_part_kernel(const signed char* __restrict__ xq,
                                     const float* __restrict__ sx,
                                     const float* __restrict__ scores,
                                     const float* __restrict__ spart,
                                     float* __restrict__ wp1,
                                     float* __restrict__ wp2) {
  __shared__ float wsx[128], s2x[128];
  __shared__ float sm[16], srz[16];
  const int d = blockIdx.x * 256 + threadIdx.x;
  const int nc = blockIdx.y;
  if (threadIdx.x < 16) {
    const int k = threadIdx.x;
    float m = -1e30f;
    #pragma unroll
    for (int c = 0; c < 8; ++c) m = fmaxf(m, spart[(k * 8 + c) * 2]);
    float S = 0.f;
    #pragma unroll
    for (int c = 0; c < 8; ++c)
      S += spart[(k * 8 + c) * 2 + 1] * __expf(spart[(k * 8 + c) * 2] - m);
    sm[k] = m; srz[k] = 1.f / S;
  }
  __syncthreads();
  if (threadIdx.x < 128) {
    const int n = nc * 128 + threadIdx.x;
    float s = 0.f;
    #pragma unroll
    for (int k = 0; k < NHEAD; ++k)
      s += __expf(scores[(size_t)k * N_PATCH + n] - sm[k]) * srz[k];
    const float sxn = sx[n];
    wsx[threadIdx.x] = s * sxn;
    s2x[threadIdx.x] = sxn;
  }
  __syncthreads();
  float a1 = 0.f, a2 = 0.f;
  for (int i = 0; i < 128; ++i) {
    const float q = (float)xq[(size_t)(nc * 128 + i) * DIM + d];
    a1 += wsx[i] * q;
    a2 += s2x[i] * q;
  }
  wp1[nc * DIM + d] = a1;
  wp2[nc * DIM + d] = a2;
}

__global__ void reduce_vec_kernel(const float* __restrict__ wp1,
                                  const float* __restrict__ wp2,
                                  float* __restrict__ y1,
                                  float* __restrict__ mvec) {
  int d = blockIdx.x * 256 + threadIdx.x;
  float s1 = 0.f, s2 = 0.f;
  #pragma unroll
  for (int i = 0; i < 64; ++i) {
    s1 += wp1[i * DIM + d];
    s2 += wp2[i * DIM + d];
  }
  y1[d] = s1;
  mvec[d] = s2 * (1.f / (float)N_PATCH);
}

// ---------------- one-dispatch GEMV: in-block split-K (4 kc x 64 j) ----------------
__global__ void gemv_fused_kernel(const float* __restrict__ in,
                                  const float* __restrict__ W,
                                  const float* __restrict__ bias,
                                  const float* __restrict__ extra, float scale,
                                  int do_relu, float* __restrict__ out,
                                  int In, int Out) {
  __shared__ float red[4][64];
  const int jl = threadIdx.x & 63, kc = threadIdx.x >> 6;
  const int j = blockIdx.x * 64 + jl;
  const int chunk = In >> 2;
  const float* Wp = W + (size_t)(kc * chunk) * Out + j;
  const float* ip = in + kc * chunk;
  float acc = 0.f;
  #pragma unroll 4
  for (int d = 0; d < chunk; ++d) acc += ip[d] * Wp[(size_t)d * Out];
  if (kc) red[kc][jl] = acc;
  __syncthreads();
  if (kc == 0) {
    float v = bias[j] + acc + red[1][jl] + red[2][jl] + red[3][jl];
    if (extra) v += extra[j];
    v *= scale;
    if (do_relu) v = fmaxf(v, 0.f);
    out[j] = v;
  }
}

// ---------------- fused: c3 = relu(c2@cW3+cb3); logits; softmax ----------------
__global__ void c3_final_kernel(const float* __restrict__ c2,
                                const float* __restrict__ W3,
                                const float* __restrict__ b3,
                                const float* __restrict__ W4,
                                const float* __restrict__ b4,
                                float* __restrict__ out) {
  __shared__ float c3s[256];
  __shared__ float logits[9];
  const int t = threadIdx.x;
  float acc = b3[t];
  #pragma unroll 4
  for (int d = 0; d < 512; ++d) acc += c2[d] * W3[(size_t)d * 256 + t];
  c3s[t] = fmaxf(acc, 0.f);
  __syncthreads();
  if (t < 9) {
    float l = b4[t];
    for (int d = 0; d < 256; ++d) l += c3s[d] * W4[d * 9 + t];
    logits[t] = l;
  }
  __syncthreads();
  if (t == 0) {
    float mx = logits[0];
    for (int j = 1; j < 9; ++j) mx = fmaxf(mx, logits[j]);
    float e[9], s = 0.f;
    for (int j = 0; j < 9; ++j) { e[j] = expf(logits[j] - mx); s += e[j]; }
    for (int j = 0; j < 9; ++j) out[j] = e[j] / s;
  }
}

extern "C" void kernel_launch(void* const* d_in, const int* in_sizes, int n_in,
                              void* d_out, int out_size, void* d_ws, size_t ws_size,
                              hipStream_t stream) {
  (void)in_sizes; (void)n_in; (void)out_size; (void)ws_size;
  const float* x   = (const float*)d_in[0];
  const float* Vw  = (const float*)d_in[1];
  const float* Vb  = (const float*)d_in[2];
  const float* Uw  = (const float*)d_in[3];
  const float* Ub  = (const float*)d_in[4];
  const float* ww  = (const float*)d_in[5];
  // d_in[6] = wb: constant per head -> softmax invariant -> unused
  const float* pW1 = (const float*)d_in[7];
  const float* pb1 = (const float*)d_in[8];
  const float* pW2 = (const float*)d_in[9];
  const float* pb2 = (const float*)d_in[10];
  const float* cW1 = (const float*)d_in[11];
  const float* cb1 = (const float*)d_in[12];
  const float* cW2 = (const float*)d_in[13];
  const float* cb2 = (const float*)d_in[14];
  const float* cW3 = (const float*)d_in[15];
  const float* cb3 = (const float*)d_in[16];
  const float* cW4 = (const float*)d_in[17];
  const float* cb4 = (const float*)d_in[18];
  float* out = (float*)d_out;

  char* ws = (char*)d_ws;
  size_t o = 0;
  auto alloc = [&](size_t bytes) -> char* {
    char* p = ws + o;
    o += (bytes + 255) & ~(size_t)255;
    return p;
  };
  signed char* xq = (signed char*)alloc((size_t)N_PATCH * DIM);       // 8 MB
  signed char* Wq = (signed char*)alloc((size_t)NHEAD * 1024 * DIM);  // 16 MB
  float* sx    = (float*)alloc(N_PATCH * 4);
  float* swp   = (float*)alloc(NHEAD * 1024 * 4);
  float* part  = (float*)alloc((size_t)4 * NHEAD * N_PATCH * 4);      // 2 MB
  float* scores= (float*)alloc((size_t)NHEAD * N_PATCH * 4);
  float* spart = (float*)alloc(NHEAD * 8 * 2 * 4);
  float* wp1   = (float*)alloc(64 * DIM * 4);
  float* wp2   = (float*)alloc(64 * DIM * 4);
  float* y1    = (float*)alloc(DIM * 4);
  float* mvec  = (float*)alloc(DIM * 4);
  float* h1    = (float*)alloc(HID * 4);
  float* aggr  = (float*)alloc(DIM * 4);
  float* c1    = (float*)alloc(1024 * 4);
  float* c2    = (float*)alloc(512 * 4);

  prep1_kernel<<<2048, 256, 0, stream>>>(x, xq, sx);
  pack_wq_kernel<<<256, 256, 0, stream>>>(Vw, Uw, swp, Wq);
  gemm_scores_kernel<<<2048, 512, 0, stream>>>(xq, Wq, sx, swp, Vb, Ub, ww, part);
  scores_part_kernel<<<128, 256, 0, stream>>>(part, scores, spart);
  weighted_part_kernel<<<dim3(4, 64), 256, 0, stream>>>(xq, sx, scores, spart, wp1, wp2);
  reduce_vec_kernel<<<4, 256, 0, stream>>>(wp1, wp2, y1, mvec);
  gemv_fused_kernel<<<8, 256, 0, stream>>>(mvec, pW1, pb1, nullptr, 1.f, 1, h1, DIM, HID);
  gemv_fused_kernel<<<16, 256, 0, stream>>>(h1, pW2, pb2, y1, 1.f / 17.f, 0, aggr, HID, DIM);
  gemv_fused_kernel<<<16, 256, 0, stream>>>(aggr, cW1, cb1, nullptr, 1.f, 1, c1, 1024, 1024);
  gemv_fused_kernel<<<8, 256, 0, stream>>>(c1, cW2, cb2, nullptr, 1.f, 1, c2, 1024, 512);
  c3_final_kernel<<<1, 256, 0, stream>>>(c2, cW3, cb3, cW4, cb4, out);
}